// Round 12
// baseline (1093.662 us; speedup 1.0000x reference)
//
#include <hip/hip_runtime.h>
#include <math.h>

#define N_NODES 100000
#define D 128
#define E_EDGES 600000
#define BN_EPS 1e-5f
#define RPS (N_NODES + 4)                 // padded rowptr stride per relation
#define N4V (N_NODES / 4)                 // 25000 int4 elements
#define SCAN_BLOCKS ((N4V + 255) / 256)   // 98

typedef __attribute__((ext_vector_type(8))) __bf16 bf16x8;
typedef __attribute__((ext_vector_type(4))) __bf16 bf16x4;
typedef __attribute__((ext_vector_type(16))) float f32x16;

// A-tile swizzle: full 4-bit XOR
__device__ __forceinline__ int qswz(int row, int q) { return q ^ (row & 15); }

// ---------------- degree histogram (all 3 relations, 4 edges/thread) ----------------
__global__ __launch_bounds__(256) void hist_kernel(
    const int* __restrict__ s0, const int* __restrict__ d0,
    const int* __restrict__ s1, const int* __restrict__ d1,
    const int* __restrict__ s2, const int* __restrict__ d2,
    int* __restrict__ outdeg, int* __restrict__ indeg)
{
    const int r = blockIdx.y;
    const int* src = (r == 0) ? s0 : ((r == 1) ? s1 : s2);
    const int* dst = (r == 0) ? d0 : ((r == 1) ? d1 : d2);
    int* od = outdeg + (size_t)r * N_NODES;
    int* id = indeg + (size_t)r * N_NODES;
    int i4 = blockIdx.x * 256 + threadIdx.x;
    if (i4 < E_EDGES / 4) {
        int4 s = ((const int4*)src)[i4];
        int4 d = ((const int4*)dst)[i4];
        atomicAdd(&od[s.x], 1); atomicAdd(&od[s.y], 1);
        atomicAdd(&od[s.z], 1); atomicAdd(&od[s.w], 1);
        atomicAdd(&id[d.x], 1); atomicAdd(&id[d.y], 1);
        atomicAdd(&id[d.z], 1); atomicAdd(&id[d.w], 1);
    }
}

// ---------------- parallel scan pass 1 ----------------
__global__ __launch_bounds__(256) void scan_part_kernel(
    const int* __restrict__ indeg, int* __restrict__ rowptr, int* __restrict__ bsum)
{
    const int r = blockIdx.y;
    const int t = threadIdx.x;
    const int lane = t & 63, wid = t >> 6;
    __shared__ int wsum[4], woff[4];
    int i4 = blockIdx.x * 256 + t;
    int4 v = (i4 < N4V) ? ((const int4*)(indeg + (size_t)r * N_NODES))[i4]
                        : make_int4(0, 0, 0, 0);
    int s0 = v.x, s1 = s0 + v.y, s2 = s1 + v.z, s3 = s2 + v.w;
    int x = s3;
    #pragma unroll
    for (int off = 1; off < 64; off <<= 1) {
        int y = __shfl_up(x, off);
        if (lane >= off) x += y;
    }
    if (lane == 63) wsum[wid] = x;
    __syncthreads();
    if (t < 4) { int s = 0; for (int j = 0; j < t; ++j) s += wsum[j]; woff[t] = s; }
    __syncthreads();
    int base = woff[wid] + (x - s3);
    if (i4 < N4V) {
        int idx = i4 * 4;
        int* rp = rowptr + (size_t)r * RPS;
        rp[idx] = base; rp[idx + 1] = base + s0; rp[idx + 2] = base + s1; rp[idx + 3] = base + s2;
    }
    if (t == 255) bsum[r * SCAN_BLOCKS + blockIdx.x] = woff[3] + wsum[3];
}

// ---------------- scan pass 2 ----------------
__global__ __launch_bounds__(256) void scan_mid_kernel(
    int* __restrict__ bsum, int* __restrict__ rowptr)
{
    const int t = threadIdx.x;
    const int lane = t & 63, wid = t >> 6;
    if (wid >= 3) return;
    const int r = wid;
    int carry = 0;
    for (int c = 0; c < (SCAN_BLOCKS + 63) / 64; ++c) {
        int idx = c * 64 + lane;
        int v = (idx < SCAN_BLOCKS) ? bsum[r * SCAN_BLOCKS + idx] : 0;
        int x = v;
        #pragma unroll
        for (int off = 1; off < 64; off <<= 1) {
            int y = __shfl_up(x, off);
            if (lane >= off) x += y;
        }
        if (idx < SCAN_BLOCKS) bsum[r * SCAN_BLOCKS + idx] = carry + x - v;
        carry += __shfl(x, 63);
    }
    if (lane == 0) rowptr[(size_t)r * RPS + N_NODES] = carry;
}

// ---------------- scan pass 3: add offsets, cursor copy, fused norms ----------------
__global__ __launch_bounds__(256) void scan_add_kernel(
    int* __restrict__ rowptr, const int* __restrict__ bsum, int* __restrict__ cursor,
    const int* __restrict__ outdeg, const int* __restrict__ indeg,
    float* __restrict__ ns, float* __restrict__ nd)
{
    const int r = blockIdx.y;
    int i4 = blockIdx.x * 256 + threadIdx.x;
    if (i4 < N4V) {
        int off = bsum[r * SCAN_BLOCKS + blockIdx.x];
        int4* rp4 = (int4*)(rowptr + (size_t)r * RPS);
        int4 v = rp4[i4];
        v.x += off; v.y += off; v.z += off; v.w += off;
        rp4[i4] = v;
        ((int4*)(cursor + (size_t)r * N_NODES))[i4] = v;
        int4 od = ((const int4*)(outdeg + (size_t)r * N_NODES))[i4];
        int4 id = ((const int4*)(indeg + (size_t)r * N_NODES))[i4];
        float4 nsv, ndv;
        nsv.x = rsqrtf((float)(od.x < 1 ? 1 : od.x));
        nsv.y = rsqrtf((float)(od.y < 1 ? 1 : od.y));
        nsv.z = rsqrtf((float)(od.z < 1 ? 1 : od.z));
        nsv.w = rsqrtf((float)(od.w < 1 ? 1 : od.w));
        ndv.x = rsqrtf((float)(id.x < 1 ? 1 : id.x));
        ndv.y = rsqrtf((float)(id.y < 1 ? 1 : id.y));
        ndv.z = rsqrtf((float)(id.z < 1 ? 1 : id.z));
        ndv.w = rsqrtf((float)(id.w < 1 ? 1 : id.w));
        ((float4*)(ns + (size_t)r * N_NODES))[i4] = nsv;
        ((float4*)(nd + (size_t)r * N_NODES))[i4] = ndv;
    }
}

// ---------------- CSR fill: edge record {src, ns[src]} ----------------
__global__ __launch_bounds__(256) void fill_kernel(
    const int* __restrict__ s0, const int* __restrict__ d0,
    const int* __restrict__ s1, const int* __restrict__ d1,
    const int* __restrict__ s2, const int* __restrict__ d2,
    const float* __restrict__ nsv,
    int* __restrict__ cursor, int2* __restrict__ eint)
{
    const int r = blockIdx.y;
    const int* src = (r == 0) ? s0 : ((r == 1) ? s1 : s2);
    const int* dst = (r == 0) ? d0 : ((r == 1) ? d1 : d2);
    int* cur = cursor + (size_t)r * N_NODES;
    int2* eg = eint + (size_t)r * E_EDGES;
    const float* ns_ = nsv + (size_t)r * N_NODES;
    int i = blockIdx.x * 256 + threadIdx.x;
    if (i < E_EDGES) {
        int s = src[i];
        int d = dst[i];
        int pos = atomicAdd(&cur[d], 1);
        eg[pos] = make_int2(s, __float_as_int(ns_[s]));
    }
}

// ---------------- W' precompute: grid (9, 8); 16 k-rows x 128 cols each ----------------
__global__ __launch_bounds__(256) void wprep_kernel(
    const float* __restrict__ Wrel, const float* __restrict__ Wfc,
    const float* __restrict__ gma, const float* __restrict__ rvar,
    __bf16* __restrict__ Whi, __bf16* __restrict__ Wlo)
{
    __shared__ float W2[128][132];
    __shared__ float W1p[16][132];
    const int b = blockIdx.x;   // l*3+r
    const int l = b / 3;
    const int by = blockIdx.y;  // k-row chunk
    const int t = threadIdx.x;

    const float* src1 = Wrel + (size_t)b * D * D;
    const float* src2 = Wfc + (size_t)l * D * D;
    #pragma unroll
    for (int p = 0; p < 16; ++p) {
        int u = t + p * 256;
        int r = u >> 5, f = u & 31;
        *(float4*)&W2[r][f * 4] = *(const float4*)(src2 + r * D + f * 4);
    }
    #pragma unroll
    for (int p = 0; p < 2; ++p) {
        int u = t + p * 256;
        int r = u >> 5, f = u & 31;
        *(float4*)&W1p[r][f * 4] = *(const float4*)(src1 + (size_t)(by * 16 + r) * D + f * 4);
    }
    __syncthreads();

    const int rl = t >> 4;
    const int cb = (t & 15) * 8;
    float acc[8];
    #pragma unroll
    for (int j = 0; j < 8; ++j) acc[j] = 0.f;
    for (int k = 0; k < 128; ++k) {
        float a = W1p[rl][k];
        #pragma unroll
        for (int j = 0; j < 8; ++j) acc[j] = fmaf(a, W2[k][cb + j], acc[j]);
    }
    const int row = by * 16 + rl;
    #pragma unroll
    for (int j = 0; j < 8; ++j) {
        int colj = cb + j;
        float s = 1.0f;
        if (l < 2) s = gma[l * D + colj] * rsqrtf(rvar[l * D + colj] + BN_EPS);
        float v = acc[j] * s;
        __bf16 hb = (__bf16)v;
        __bf16 lb = (__bf16)(v - (float)hb);
        Whi[((size_t)b * D + colj) * D + row] = hb;
        Wlo[((size_t)b * D + colj) * D + row] = lb;
    }
}

// ---------------- bias precompute ----------------
__global__ __launch_bounds__(128) void bias_prep_kernel(
    const float* __restrict__ brel, const float* __restrict__ Wfc,
    const float* __restrict__ bfc,
    const float* __restrict__ gma, const float* __restrict__ bta,
    const float* __restrict__ rmean, const float* __restrict__ rvar,
    float* __restrict__ bvec)
{
    int j = threadIdx.x;
    int l = blockIdx.x;
    float acc = bfc[l * D + j];
    for (int k = 0; k < D; ++k) {
        float bs = brel[(l * 3 + 0) * D + k] + brel[(l * 3 + 1) * D + k] + brel[(l * 3 + 2) * D + k];
        acc = fmaf(bs, Wfc[((size_t)l * D + k) * D + j], acc);
    }
    if (l < 2) {
        float s = gma[l * D + j] * rsqrtf(rvar[l * D + j] + BN_EPS);
        acc = acc * s + (bta[l * D + j] - rmean[l * D + j] * s);
    }
    bvec[l * D + j] = acc;
}

// 16 FMAs of one edge's 4 float4 into accumulators a0..a3
#define FMA16(W_, P_, Q_, R_, S_)                                              \
    a0.x = fmaf(W_, P_.x, a0.x); a0.y = fmaf(W_, P_.y, a0.y);                  \
    a0.z = fmaf(W_, P_.z, a0.z); a0.w = fmaf(W_, P_.w, a0.w);                  \
    a1.x = fmaf(W_, Q_.x, a1.x); a1.y = fmaf(W_, Q_.y, a1.y);                  \
    a1.z = fmaf(W_, Q_.z, a1.z); a1.w = fmaf(W_, Q_.w, a1.w);                  \
    a2.x = fmaf(W_, R_.x, a2.x); a2.y = fmaf(W_, R_.y, a2.y);                  \
    a2.z = fmaf(W_, R_.z, a2.z); a2.w = fmaf(W_, R_.w, a2.w);                  \
    a3.x = fmaf(W_, S_.x, a3.x); a3.y = fmaf(W_, S_.y, a3.y);                  \
    a3.z = fmaf(W_, S_.z, a3.z); a3.w = fmaf(W_, S_.w, a3.w);

// ---------------- fused layer: gather -> A in LDS (hi/lo) -> MFMA with B direct-from-L2 ----------------
// BM=64 rows/block, 512 threads = 8 waves; wave w: rows (w&1)*32..+31, cols (w>>1)*32..+31.
// LDS 32 KB (A only) -> 4 blocks/CU = 32 waves/CU (100% cap). B fragments read from global
// (W' is 128KB/relation, L2-resident); ks-loop is barrier-free (2 barriers per relation total).
__global__ __launch_bounds__(512, 8) void fused_layer_kernel(
    const float* __restrict__ h,
    const int* __restrict__ rowptr,   // [3][RPS]
    const int2* __restrict__ eint,    // [3][E] {src, ns[src]}
    const float* __restrict__ ndv,    // [3][N]
    const __bf16* __restrict__ Whi,   // [3][col][k], this layer
    const __bf16* __restrict__ Wlo,
    float* __restrict__ out, const float* __restrict__ bias, int relu)
{
    __shared__ __bf16 Ah[64 * 128];    // 16 KB
    __shared__ __bf16 Al[64 * 128];    // 16 KB

    const int t = threadIdx.x;
    const int lane = t & 63;
    const int wid = t >> 6;           // 0..7
    const int wrow = wid & 1;         // 32-row half
    const int wcol = wid >> 1;        // 32-col quarter
    const int row0 = blockIdx.x * 64;
    const int g = t >> 3;             // 64 gather groups, 1 row each
    const int gl = t & 7;             // lane in group: k-cols gl*4 + 32*j

    f32x16 acc;
    #pragma unroll
    for (int i = 0; i < 16; ++i) acc[i] = 0.0f;

    const int arow = lane & 31;
    const int kgrp = lane >> 5;
    const int colg = wcol * 32 + arow;

    for (int r = 0; r < 3; ++r) {
        const int* rp = rowptr + (size_t)r * RPS;
        const int2* eg = eint + (size_t)r * E_EDGES;
        const float* nd_ = ndv + (size_t)r * N_NODES;

        // ---- gather: 1 row per 8-lane group, 4-edge burst (R10-proven) ----
        {
            int rowl = g;
            int grow = row0 + rowl;
            float4 a0 = {0,0,0,0}, a1 = {0,0,0,0}, a2 = {0,0,0,0}, a3 = {0,0,0,0};
            if (grow < N_NODES) {
                int beg = rp[grow], end = rp[grow + 1];
                float sc = nd_[grow];
                int e = beg;
                for (; e + 4 <= end; e += 4) {
                    int2 q0 = eg[e], q1 = eg[e + 1], q2 = eg[e + 2], q3 = eg[e + 3];
                    const float* p0 = h + (size_t)q0.x * D + gl * 4;
                    const float* p1 = h + (size_t)q1.x * D + gl * 4;
                    const float* p2 = h + (size_t)q2.x * D + gl * 4;
                    const float* p3 = h + (size_t)q3.x * D + gl * 4;
                    float4 u00 = *(const float4*)(p0),      u01 = *(const float4*)(p0 + 32);
                    float4 u02 = *(const float4*)(p0 + 64), u03 = *(const float4*)(p0 + 96);
                    float4 u10 = *(const float4*)(p1),      u11 = *(const float4*)(p1 + 32);
                    float4 u12 = *(const float4*)(p1 + 64), u13 = *(const float4*)(p1 + 96);
                    float4 u20 = *(const float4*)(p2),      u21 = *(const float4*)(p2 + 32);
                    float4 u22 = *(const float4*)(p2 + 64), u23 = *(const float4*)(p2 + 96);
                    float4 u30 = *(const float4*)(p3),      u31 = *(const float4*)(p3 + 32);
                    float4 u32 = *(const float4*)(p3 + 64), u33 = *(const float4*)(p3 + 96);
                    float wa = __int_as_float(q0.y), wb = __int_as_float(q1.y);
                    float wc = __int_as_float(q2.y), wd = __int_as_float(q3.y);
                    FMA16(wa, u00, u01, u02, u03);
                    FMA16(wb, u10, u11, u12, u13);
                    FMA16(wc, u20, u21, u22, u23);
                    FMA16(wd, u30, u31, u32, u33);
                }
                if (e + 2 <= end) {
                    int2 q0 = eg[e], q1 = eg[e + 1];
                    const float* p0 = h + (size_t)q0.x * D + gl * 4;
                    const float* p1 = h + (size_t)q1.x * D + gl * 4;
                    float4 u00 = *(const float4*)(p0),      u01 = *(const float4*)(p0 + 32);
                    float4 u02 = *(const float4*)(p0 + 64), u03 = *(const float4*)(p0 + 96);
                    float4 u10 = *(const float4*)(p1),      u11 = *(const float4*)(p1 + 32);
                    float4 u12 = *(const float4*)(p1 + 64), u13 = *(const float4*)(p1 + 96);
                    float wa = __int_as_float(q0.y), wb = __int_as_float(q1.y);
                    FMA16(wa, u00, u01, u02, u03);
                    FMA16(wb, u10, u11, u12, u13);
                    e += 2;
                }
                if (e < end) {
                    int2 q0 = eg[e];
                    const float* p0 = h + (size_t)q0.x * D + gl * 4;
                    float4 u00 = *(const float4*)(p0),      u01 = *(const float4*)(p0 + 32);
                    float4 u02 = *(const float4*)(p0 + 64), u03 = *(const float4*)(p0 + 96);
                    float wa = __int_as_float(q0.y);
                    FMA16(wa, u00, u01, u02, u03);
                }
                a0.x *= sc; a0.y *= sc; a0.z *= sc; a0.w *= sc;
                a1.x *= sc; a1.y *= sc; a1.z *= sc; a1.w *= sc;
                a2.x *= sc; a2.y *= sc; a2.z *= sc; a2.w *= sc;
                a3.x *= sc; a3.y *= sc; a3.z *= sc; a3.w *= sc;
            }
            float4 av[4] = {a0, a1, a2, a3};
            #pragma unroll
            for (int j = 0; j < 4; ++j) {
                int q = (gl >> 1) + 4 * j;
                int idx = rowl * 128 + qswz(rowl, q) * 8 + (gl & 1) * 4;
                bf16x4 hv, lv;
                float* ap = &av[j].x;
                #pragma unroll
                for (int c = 0; c < 4; ++c) {
                    __bf16 hb = (__bf16)ap[c];
                    hv[c] = hb;
                    lv[c] = (__bf16)(ap[c] - (float)hb);
                }
                *(bf16x4*)&Ah[idx] = hv;
                *(bf16x4*)&Al[idx] = lv;
            }
        }
        __syncthreads();   // A tile complete

        // ---- MFMA over 4 K-slices; B fragments straight from global (L2-hot W') ----
        const __bf16* bh_base = Whi + (size_t)r * D * D + (size_t)colg * D;
        const __bf16* bl_base = Wlo + (size_t)r * D * D + (size_t)colg * D;
        #pragma unroll
        for (int ks = 0; ks < 4; ++ks) {
            #pragma unroll
            for (int ksub = 0; ksub < 2; ++ksub) {
                int ac = ksub * 2 + kgrp;
                bf16x8 bhv = *(const bf16x8*)(bh_base + ks * 32 + ac * 8);
                bf16x8 blv = *(const bf16x8*)(bl_base + ks * 32 + ac * 8);
                int arow_g = wrow * 32 + arow;
                int aidx = arow_g * 128 + qswz(arow_g, ks * 4 + ac) * 8;
                bf16x8 ahv = *(const bf16x8*)&Ah[aidx];
                bf16x8 alv = *(const bf16x8*)&Al[aidx];
                acc = __builtin_amdgcn_mfma_f32_32x32x16_bf16(ahv, bhv, acc, 0, 0, 0);
                acc = __builtin_amdgcn_mfma_f32_32x32x16_bf16(ahv, blv, acc, 0, 0, 0);
                acc = __builtin_amdgcn_mfma_f32_32x32x16_bf16(alv, bhv, acc, 0, 0, 0);
            }
        }
        __syncthreads();   // MFMA reads done before next relation's gather overwrites A
    }

    // ---- epilogue: bias (+ ReLU), single write ----
    const int colb = lane & 31;
    const int rq = lane >> 5;
    {
        int colgo = wcol * 32 + colb;
        float bv = bias[colgo];
        #pragma unroll
        for (int reg = 0; reg < 16; ++reg) {
            int rowl = wrow * 32 + (reg & 3) + 8 * (reg >> 2) + 4 * rq;
            int grow = row0 + rowl;
            if (grow < N_NODES) {
                float z = acc[reg] + bv;
                if (relu) z = fmaxf(z, 0.f);
                out[(size_t)grow * D + colgo] = z;
            }
        }
    }
}

// ---------------- launch ----------------
extern "C" void kernel_launch(void* const* d_in, const int* in_sizes, int n_in,
                              void* d_out, int out_size, void* d_ws, size_t ws_size,
                              hipStream_t stream)
{
    const float* x      = (const float*)d_in[0];
    const int* seq_src  = (const int*)d_in[1];
    const int* seq_dst  = (const int*)d_in[2];
    const int* knn_src  = (const int*)d_in[3];
    const int* knn_dst  = (const int*)d_in[4];
    const int* dis_src  = (const int*)d_in[5];
    const int* dis_dst  = (const int*)d_in[6];
    const float* Wrel   = (const float*)d_in[7];   // [3][3][128][128]
    const float* brel   = (const float*)d_in[8];   // [3][3][128]
    const float* Wfc    = (const float*)d_in[9];   // [3][128][128]
    const float* bfc    = (const float*)d_in[10];  // [3][128]
    const float* gma    = (const float*)d_in[11];  // [2][128]
    const float* bta    = (const float*)d_in[12];
    const float* rmean  = (const float*)d_in[13];
    const float* rvar   = (const float*)d_in[14];
    float* out = (float*)d_out;

    const size_t ND = (size_t)N_NODES * D;
    float* ws   = (float*)d_ws;
    float* h0   = ws;                         // N*D
    float* h1   = h0 + ND;                    // N*D
    float* ns_  = h1 + ND;                    // 3*N
    float* nd_  = ns_ + 3 * N_NODES;          // 3*N
    float* bvec = nd_ + 3 * N_NODES;          // 3*128
    __bf16* Whi = (__bf16*)(bvec + 3 * D);    // 9*128*128
    __bf16* Wlo = Whi + (size_t)9 * D * D;
    int* outdeg = (int*)(Wlo + (size_t)9 * D * D);   // 3*N
    int* indeg  = outdeg + 3 * N_NODES;               // 3*N
    int* rowptr = indeg + 3 * N_NODES;                // 3*RPS
    int* cursor = rowptr + 3 * RPS;                   // 3*N
    int* bsum   = cursor + 3 * N_NODES;               // 3*SCAN_BLOCKS
    int2* eint  = (int2*)(bsum + 3 * SCAN_BLOCKS + 2); // 3*E {src, w} (8B aligned)

    // ---- graph preprocessing ----
    hipMemsetAsync(outdeg, 0, (size_t)6 * N_NODES * sizeof(int), stream);
    hist_kernel<<<dim3((E_EDGES / 4 + 255) / 256, 3), 256, 0, stream>>>(
        seq_src, seq_dst, knn_src, knn_dst, dis_src, dis_dst, outdeg, indeg);
    scan_part_kernel<<<dim3(SCAN_BLOCKS, 3), 256, 0, stream>>>(indeg, rowptr, bsum);
    scan_mid_kernel<<<1, 256, 0, stream>>>(bsum, rowptr);
    scan_add_kernel<<<dim3(SCAN_BLOCKS, 3), 256, 0, stream>>>(
        rowptr, bsum, cursor, outdeg, indeg, ns_, nd_);
    fill_kernel<<<dim3((E_EDGES + 255) / 256, 3), 256, 0, stream>>>(
        seq_src, seq_dst, knn_src, knn_dst, dis_src, dis_dst, ns_, cursor, eint);

    // ---- weight/bias precompute ----
    wprep_kernel<<<dim3(9, 8), 256, 0, stream>>>(Wrel, Wfc, gma, rvar, Whi, Wlo);
    bias_prep_kernel<<<3, 128, 0, stream>>>(brel, Wfc, bfc, gma, bta, rmean, rvar, bvec);

    // ---- layers (fully fused) ----
    const int GB = (N_NODES + 63) / 64;   // 1563
    fused_layer_kernel<<<GB, 512, 0, stream>>>(
        x, rowptr, eint, nd_, Whi, Wlo, h0, bvec, 1);
    fused_layer_kernel<<<GB, 512, 0, stream>>>(
        h0, rowptr, eint, nd_, Whi + (size_t)3 * D * D, Wlo + (size_t)3 * D * D,
        h1, bvec + D, 1);
    fused_layer_kernel<<<GB, 512, 0, stream>>>(
        h1, rowptr, eint, nd_, Whi + (size_t)6 * D * D, Wlo + (size_t)6 * D * D,
        out, bvec + 2 * D, 0);
}

// Round 13
// 1001.912 us; speedup vs baseline: 1.0916x; 1.0916x over previous
//
#include <hip/hip_runtime.h>
#include <math.h>

#define N_NODES 100000
#define D 128
#define E_EDGES 600000
#define BN_EPS 1e-5f
#define RPS (N_NODES + 4)                 // padded rowptr stride per relation
#define N4V (N_NODES / 4)                 // 25000 int4 elements
#define SCAN_BLOCKS ((N4V + 255) / 256)   // 98

typedef __attribute__((ext_vector_type(8))) __bf16 bf16x8;
typedef __attribute__((ext_vector_type(4))) __bf16 bf16x4;
typedef __attribute__((ext_vector_type(16))) float f32x16;

// A-tile swizzle: full 4-bit XOR
__device__ __forceinline__ int qswz(int row, int q) { return q ^ (row & 15); }

// ---------------- degree histogram (all 3 relations, 4 edges/thread) ----------------
__global__ __launch_bounds__(256) void hist_kernel(
    const int* __restrict__ s0, const int* __restrict__ d0,
    const int* __restrict__ s1, const int* __restrict__ d1,
    const int* __restrict__ s2, const int* __restrict__ d2,
    int* __restrict__ outdeg, int* __restrict__ indeg)
{
    const int r = blockIdx.y;
    const int* src = (r == 0) ? s0 : ((r == 1) ? s1 : s2);
    const int* dst = (r == 0) ? d0 : ((r == 1) ? d1 : d2);
    int* od = outdeg + (size_t)r * N_NODES;
    int* id = indeg + (size_t)r * N_NODES;
    int i4 = blockIdx.x * 256 + threadIdx.x;
    if (i4 < E_EDGES / 4) {
        int4 s = ((const int4*)src)[i4];
        int4 d = ((const int4*)dst)[i4];
        atomicAdd(&od[s.x], 1); atomicAdd(&od[s.y], 1);
        atomicAdd(&od[s.z], 1); atomicAdd(&od[s.w], 1);
        atomicAdd(&id[d.x], 1); atomicAdd(&id[d.y], 1);
        atomicAdd(&id[d.z], 1); atomicAdd(&id[d.w], 1);
    }
}

// ---------------- parallel scan pass 1 ----------------
__global__ __launch_bounds__(256) void scan_part_kernel(
    const int* __restrict__ indeg, int* __restrict__ rowptr, int* __restrict__ bsum)
{
    const int r = blockIdx.y;
    const int t = threadIdx.x;
    const int lane = t & 63, wid = t >> 6;
    __shared__ int wsum[4], woff[4];
    int i4 = blockIdx.x * 256 + t;
    int4 v = (i4 < N4V) ? ((const int4*)(indeg + (size_t)r * N_NODES))[i4]
                        : make_int4(0, 0, 0, 0);
    int s0 = v.x, s1 = s0 + v.y, s2 = s1 + v.z, s3 = s2 + v.w;
    int x = s3;
    #pragma unroll
    for (int off = 1; off < 64; off <<= 1) {
        int y = __shfl_up(x, off);
        if (lane >= off) x += y;
    }
    if (lane == 63) wsum[wid] = x;
    __syncthreads();
    if (t < 4) { int s = 0; for (int j = 0; j < t; ++j) s += wsum[j]; woff[t] = s; }
    __syncthreads();
    int base = woff[wid] + (x - s3);
    if (i4 < N4V) {
        int idx = i4 * 4;
        int* rp = rowptr + (size_t)r * RPS;
        rp[idx] = base; rp[idx + 1] = base + s0; rp[idx + 2] = base + s1; rp[idx + 3] = base + s2;
    }
    if (t == 255) bsum[r * SCAN_BLOCKS + blockIdx.x] = woff[3] + wsum[3];
}

// ---------------- scan pass 2 ----------------
__global__ __launch_bounds__(256) void scan_mid_kernel(
    int* __restrict__ bsum, int* __restrict__ rowptr)
{
    const int t = threadIdx.x;
    const int lane = t & 63, wid = t >> 6;
    if (wid >= 3) return;
    const int r = wid;
    int carry = 0;
    for (int c = 0; c < (SCAN_BLOCKS + 63) / 64; ++c) {
        int idx = c * 64 + lane;
        int v = (idx < SCAN_BLOCKS) ? bsum[r * SCAN_BLOCKS + idx] : 0;
        int x = v;
        #pragma unroll
        for (int off = 1; off < 64; off <<= 1) {
            int y = __shfl_up(x, off);
            if (lane >= off) x += y;
        }
        if (idx < SCAN_BLOCKS) bsum[r * SCAN_BLOCKS + idx] = carry + x - v;
        carry += __shfl(x, 63);
    }
    if (lane == 0) rowptr[(size_t)r * RPS + N_NODES] = carry;
}

// ---------------- scan pass 3: add offsets, cursor copy, fused norms ----------------
__global__ __launch_bounds__(256) void scan_add_kernel(
    int* __restrict__ rowptr, const int* __restrict__ bsum, int* __restrict__ cursor,
    const int* __restrict__ outdeg, const int* __restrict__ indeg,
    float* __restrict__ ns, float* __restrict__ nd)
{
    const int r = blockIdx.y;
    int i4 = blockIdx.x * 256 + threadIdx.x;
    if (i4 < N4V) {
        int off = bsum[r * SCAN_BLOCKS + blockIdx.x];
        int4* rp4 = (int4*)(rowptr + (size_t)r * RPS);
        int4 v = rp4[i4];
        v.x += off; v.y += off; v.z += off; v.w += off;
        rp4[i4] = v;
        ((int4*)(cursor + (size_t)r * N_NODES))[i4] = v;
        int4 od = ((const int4*)(outdeg + (size_t)r * N_NODES))[i4];
        int4 id = ((const int4*)(indeg + (size_t)r * N_NODES))[i4];
        float4 nsv, ndv;
        nsv.x = rsqrtf((float)(od.x < 1 ? 1 : od.x));
        nsv.y = rsqrtf((float)(od.y < 1 ? 1 : od.y));
        nsv.z = rsqrtf((float)(od.z < 1 ? 1 : od.z));
        nsv.w = rsqrtf((float)(od.w < 1 ? 1 : od.w));
        ndv.x = rsqrtf((float)(id.x < 1 ? 1 : id.x));
        ndv.y = rsqrtf((float)(id.y < 1 ? 1 : id.y));
        ndv.z = rsqrtf((float)(id.z < 1 ? 1 : id.z));
        ndv.w = rsqrtf((float)(id.w < 1 ? 1 : id.w));
        ((float4*)(ns + (size_t)r * N_NODES))[i4] = nsv;
        ((float4*)(nd + (size_t)r * N_NODES))[i4] = ndv;
    }
}

// ---------------- CSR fill: edge record {src, ns[src]} ----------------
__global__ __launch_bounds__(256) void fill_kernel(
    const int* __restrict__ s0, const int* __restrict__ d0,
    const int* __restrict__ s1, const int* __restrict__ d1,
    const int* __restrict__ s2, const int* __restrict__ d2,
    const float* __restrict__ nsv,
    int* __restrict__ cursor, int2* __restrict__ eint)
{
    const int r = blockIdx.y;
    const int* src = (r == 0) ? s0 : ((r == 1) ? s1 : s2);
    const int* dst = (r == 0) ? d0 : ((r == 1) ? d1 : d2);
    int* cur = cursor + (size_t)r * N_NODES;
    int2* eg = eint + (size_t)r * E_EDGES;
    const float* ns_ = nsv + (size_t)r * N_NODES;
    int i = blockIdx.x * 256 + threadIdx.x;
    if (i < E_EDGES) {
        int s = src[i];
        int d = dst[i];
        int pos = atomicAdd(&cur[d], 1);
        eg[pos] = make_int2(s, __float_as_int(ns_[s]));
    }
}

// ---------------- W' precompute: grid (9, 8); 16 k-rows x 128 cols each ----------------
__global__ __launch_bounds__(256) void wprep_kernel(
    const float* __restrict__ Wrel, const float* __restrict__ Wfc,
    const float* __restrict__ gma, const float* __restrict__ rvar,
    __bf16* __restrict__ Whi, __bf16* __restrict__ Wlo)
{
    __shared__ float W2[128][132];
    __shared__ float W1p[16][132];
    const int b = blockIdx.x;   // l*3+r
    const int l = b / 3;
    const int by = blockIdx.y;  // k-row chunk
    const int t = threadIdx.x;

    const float* src1 = Wrel + (size_t)b * D * D;
    const float* src2 = Wfc + (size_t)l * D * D;
    #pragma unroll
    for (int p = 0; p < 16; ++p) {
        int u = t + p * 256;
        int r = u >> 5, f = u & 31;
        *(float4*)&W2[r][f * 4] = *(const float4*)(src2 + r * D + f * 4);
    }
    #pragma unroll
    for (int p = 0; p < 2; ++p) {
        int u = t + p * 256;
        int r = u >> 5, f = u & 31;
        *(float4*)&W1p[r][f * 4] = *(const float4*)(src1 + (size_t)(by * 16 + r) * D + f * 4);
    }
    __syncthreads();

    const int rl = t >> 4;
    const int cb = (t & 15) * 8;
    float acc[8];
    #pragma unroll
    for (int j = 0; j < 8; ++j) acc[j] = 0.f;
    for (int k = 0; k < 128; ++k) {
        float a = W1p[rl][k];
        #pragma unroll
        for (int j = 0; j < 8; ++j) acc[j] = fmaf(a, W2[k][cb + j], acc[j]);
    }
    const int row = by * 16 + rl;
    #pragma unroll
    for (int j = 0; j < 8; ++j) {
        int colj = cb + j;
        float s = 1.0f;
        if (l < 2) s = gma[l * D + colj] * rsqrtf(rvar[l * D + colj] + BN_EPS);
        float v = acc[j] * s;
        __bf16 hb = (__bf16)v;
        __bf16 lb = (__bf16)(v - (float)hb);
        Whi[((size_t)b * D + colj) * D + row] = hb;
        Wlo[((size_t)b * D + colj) * D + row] = lb;
    }
}

// ---------------- bias precompute ----------------
__global__ __launch_bounds__(128) void bias_prep_kernel(
    const float* __restrict__ brel, const float* __restrict__ Wfc,
    const float* __restrict__ bfc,
    const float* __restrict__ gma, const float* __restrict__ bta,
    const float* __restrict__ rmean, const float* __restrict__ rvar,
    float* __restrict__ bvec)
{
    int j = threadIdx.x;
    int l = blockIdx.x;
    float acc = bfc[l * D + j];
    for (int k = 0; k < D; ++k) {
        float bs = brel[(l * 3 + 0) * D + k] + brel[(l * 3 + 1) * D + k] + brel[(l * 3 + 2) * D + k];
        acc = fmaf(bs, Wfc[((size_t)l * D + k) * D + j], acc);
    }
    if (l < 2) {
        float s = gma[l * D + j] * rsqrtf(rvar[l * D + j] + BN_EPS);
        acc = acc * s + (bta[l * D + j] - rmean[l * D + j] * s);
    }
    bvec[l * D + j] = acc;
}

// 16 FMAs of one edge's 4 float4 into accumulators a0..a3
#define FMA16(W_, P_, Q_, R_, S_)                                              \
    a0.x = fmaf(W_, P_.x, a0.x); a0.y = fmaf(W_, P_.y, a0.y);                  \
    a0.z = fmaf(W_, P_.z, a0.z); a0.w = fmaf(W_, P_.w, a0.w);                  \
    a1.x = fmaf(W_, Q_.x, a1.x); a1.y = fmaf(W_, Q_.y, a1.y);                  \
    a1.z = fmaf(W_, Q_.z, a1.z); a1.w = fmaf(W_, Q_.w, a1.w);                  \
    a2.x = fmaf(W_, R_.x, a2.x); a2.y = fmaf(W_, R_.y, a2.y);                  \
    a2.z = fmaf(W_, R_.z, a2.z); a2.w = fmaf(W_, R_.w, a2.w);                  \
    a3.x = fmaf(W_, S_.x, a3.x); a3.y = fmaf(W_, S_.y, a3.y);                  \
    a3.z = fmaf(W_, S_.z, a3.z); a3.w = fmaf(W_, S_.w, a3.w);

// ---------------- fused layer: gather (SGB-clustered loads) -> A LDS hi/lo -> MFMA, B from L2 ----------------
// BM=128 rows/block, 512 threads = 8 waves; wave w: rows (w&3)*32..+31, cols (w>>2)*64..+63.
// LDS 64 KB (A only) -> 2 blocks/CU; B fragments direct from global (W' L2-resident);
// ks-loop barrier-free: 2 barriers per relation total.
__global__ __launch_bounds__(512, 4) void fused_layer_kernel(
    const float* __restrict__ h,
    const int* __restrict__ rowptr,   // [3][RPS]
    const int2* __restrict__ eint,    // [3][E] {src, ns[src]}
    const float* __restrict__ ndv,    // [3][N]
    const __bf16* __restrict__ Whi,   // [3][col][k], this layer
    const __bf16* __restrict__ Wlo,
    float* __restrict__ out, const float* __restrict__ bias, int relu)
{
    __shared__ __bf16 Ah[128 * 128];   // 32 KB
    __shared__ __bf16 Al[128 * 128];   // 32 KB

    const int t = threadIdx.x;
    const int lane = t & 63;
    const int wid = t >> 6;           // 0..7
    const int wrow = wid & 3;         // 32-row quarter
    const int wcol = wid >> 2;        // 64-col half
    const int row0 = blockIdx.x * 128;
    const int g = t >> 3;             // 64 gather groups, 1 row each (x2 pass below)
    const int gl = t & 7;             // lane in group: k-cols gl*4 + 32*j

    f32x16 acc[2];
    #pragma unroll
    for (int nt = 0; nt < 2; ++nt)
        #pragma unroll
        for (int i = 0; i < 16; ++i) acc[nt][i] = 0.0f;

    const int arow = lane & 31;
    const int kgrp = lane >> 5;

    for (int r = 0; r < 3; ++r) {
        const int* rp = rowptr + (size_t)r * RPS;
        const int2* eg = eint + (size_t)r * E_EDGES;
        const float* nd_ = ndv + (size_t)r * N_NODES;

        // ---- gather: each 8-lane group does rows g*2 and g*2+1, 4-edge SGB-clustered burst ----
        #pragma unroll
        for (int rr = 0; rr < 2; ++rr) {
            int rowl = g * 2 + rr;
            int grow = row0 + rowl;
            float4 a0 = {0,0,0,0}, a1 = {0,0,0,0}, a2 = {0,0,0,0}, a3 = {0,0,0,0};
            if (grow < N_NODES) {
                int beg = rp[grow], end = rp[grow + 1];
                float sc = nd_[grow];
                int e = beg;
                for (; e + 4 <= end; e += 4) {
                    int2 q0 = eg[e], q1 = eg[e + 1], q2 = eg[e + 2], q3 = eg[e + 3];
                    const float* p0 = h + (size_t)q0.x * D + gl * 4;
                    const float* p1 = h + (size_t)q1.x * D + gl * 4;
                    const float* p2 = h + (size_t)q2.x * D + gl * 4;
                    const float* p3 = h + (size_t)q3.x * D + gl * 4;
                    float4 u00 = *(const float4*)(p0),      u01 = *(const float4*)(p0 + 32);
                    float4 u02 = *(const float4*)(p0 + 64), u03 = *(const float4*)(p0 + 96);
                    float4 u10 = *(const float4*)(p1),      u11 = *(const float4*)(p1 + 32);
                    float4 u12 = *(const float4*)(p1 + 64), u13 = *(const float4*)(p1 + 96);
                    float4 u20 = *(const float4*)(p2),      u21 = *(const float4*)(p2 + 32);
                    float4 u22 = *(const float4*)(p2 + 64), u23 = *(const float4*)(p2 + 96);
                    float4 u30 = *(const float4*)(p3),      u31 = *(const float4*)(p3 + 32);
                    float4 u32 = *(const float4*)(p3 + 64), u33 = *(const float4*)(p3 + 96);
                    float wa = __int_as_float(q0.y), wb = __int_as_float(q1.y);
                    float wc = __int_as_float(q2.y), wd = __int_as_float(q3.y);
                    FMA16(wa, u00, u01, u02, u03);
                    FMA16(wb, u10, u11, u12, u13);
                    FMA16(wc, u20, u21, u22, u23);
                    FMA16(wd, u30, u31, u32, u33);
                    // T19: force {eg loads} -> {addr} -> {16 h-loads clustered} -> {FMA}
                    __builtin_amdgcn_sched_group_barrier(0x020, 4, 0);   // VMEM_READ: eg
                    __builtin_amdgcn_sched_group_barrier(0x002, 40, 0);  // VALU: addr calc
                    __builtin_amdgcn_sched_group_barrier(0x020, 16, 0);  // VMEM_READ: h x16
                    __builtin_amdgcn_sched_group_barrier(0x002, 200, 0); // VALU: FMAs
                }
                if (e + 2 <= end) {
                    int2 q0 = eg[e], q1 = eg[e + 1];
                    const float* p0 = h + (size_t)q0.x * D + gl * 4;
                    const float* p1 = h + (size_t)q1.x * D + gl * 4;
                    float4 u00 = *(const float4*)(p0),      u01 = *(const float4*)(p0 + 32);
                    float4 u02 = *(const float4*)(p0 + 64), u03 = *(const float4*)(p0 + 96);
                    float4 u10 = *(const float4*)(p1),      u11 = *(const float4*)(p1 + 32);
                    float4 u12 = *(const float4*)(p1 + 64), u13 = *(const float4*)(p1 + 96);
                    float wa = __int_as_float(q0.y), wb = __int_as_float(q1.y);
                    FMA16(wa, u00, u01, u02, u03);
                    FMA16(wb, u10, u11, u12, u13);
                    e += 2;
                }
                if (e < end) {
                    int2 q0 = eg[e];
                    const float* p0 = h + (size_t)q0.x * D + gl * 4;
                    float4 u00 = *(const float4*)(p0),      u01 = *(const float4*)(p0 + 32);
                    float4 u02 = *(const float4*)(p0 + 64), u03 = *(const float4*)(p0 + 96);
                    float wa = __int_as_float(q0.y);
                    FMA16(wa, u00, u01, u02, u03);
                }
                a0.x *= sc; a0.y *= sc; a0.z *= sc; a0.w *= sc;
                a1.x *= sc; a1.y *= sc; a1.z *= sc; a1.w *= sc;
                a2.x *= sc; a2.y *= sc; a2.z *= sc; a2.w *= sc;
                a3.x *= sc; a3.y *= sc; a3.z *= sc; a3.w *= sc;
            }
            float4 av[4] = {a0, a1, a2, a3};
            #pragma unroll
            for (int j = 0; j < 4; ++j) {
                int q = (gl >> 1) + 4 * j;
                int idx = rowl * 128 + qswz(rowl, q) * 8 + (gl & 1) * 4;
                bf16x4 hv, lv;
                float* ap = &av[j].x;
                #pragma unroll
                for (int c = 0; c < 4; ++c) {
                    __bf16 hb = (__bf16)ap[c];
                    hv[c] = hb;
                    lv[c] = (__bf16)(ap[c] - (float)hb);
                }
                *(bf16x4*)&Ah[idx] = hv;
                *(bf16x4*)&Al[idx] = lv;
            }
        }
        __syncthreads();   // A tile complete

        // ---- MFMA over 4 K-slices, barrier-free; B fragments direct from L2-hot W' ----
        {
            const __bf16* bh0 = Whi + (size_t)r * D * D + (size_t)(wcol * 64 + arow) * D;
            const __bf16* bl0 = Wlo + (size_t)r * D * D + (size_t)(wcol * 64 + arow) * D;
            const __bf16* bh1 = bh0 + 32 * D;
            const __bf16* bl1 = bl0 + 32 * D;
            #pragma unroll
            for (int ks = 0; ks < 4; ++ks) {
                #pragma unroll
                for (int ksub = 0; ksub < 2; ++ksub) {
                    int ac = ksub * 2 + kgrp;
                    int off = ks * 32 + ac * 8;
                    bf16x8 b0h = *(const bf16x8*)(bh0 + off);
                    bf16x8 b0l = *(const bf16x8*)(bl0 + off);
                    bf16x8 b1h = *(const bf16x8*)(bh1 + off);
                    bf16x8 b1l = *(const bf16x8*)(bl1 + off);
                    int arow_g = wrow * 32 + arow;
                    int aidx = arow_g * 128 + qswz(arow_g, ks * 4 + ac) * 8;
                    bf16x8 ahv = *(const bf16x8*)&Ah[aidx];
                    bf16x8 alv = *(const bf16x8*)&Al[aidx];
                    acc[0] = __builtin_amdgcn_mfma_f32_32x32x16_bf16(ahv, b0h, acc[0], 0, 0, 0);
                    acc[0] = __builtin_amdgcn_mfma_f32_32x32x16_bf16(ahv, b0l, acc[0], 0, 0, 0);
                    acc[0] = __builtin_amdgcn_mfma_f32_32x32x16_bf16(alv, b0h, acc[0], 0, 0, 0);
                    acc[1] = __builtin_amdgcn_mfma_f32_32x32x16_bf16(ahv, b1h, acc[1], 0, 0, 0);
                    acc[1] = __builtin_amdgcn_mfma_f32_32x32x16_bf16(ahv, b1l, acc[1], 0, 0, 0);
                    acc[1] = __builtin_amdgcn_mfma_f32_32x32x16_bf16(alv, b1h, acc[1], 0, 0, 0);
                }
            }
        }
        __syncthreads();   // MFMA reads done before next relation's gather overwrites A
    }

    // ---- epilogue: bias (+ ReLU), single write ----
    const int colb = lane & 31;
    const int rq = lane >> 5;
    #pragma unroll
    for (int nt = 0; nt < 2; ++nt) {
        int colg = wcol * 64 + nt * 32 + colb;
        float bv = bias[colg];
        #pragma unroll
        for (int reg = 0; reg < 16; ++reg) {
            int rowl = wrow * 32 + (reg & 3) + 8 * (reg >> 2) + 4 * rq;
            int grow = row0 + rowl;
            if (grow < N_NODES) {
                float z = acc[nt][reg] + bv;
                if (relu) z = fmaxf(z, 0.f);
                out[(size_t)grow * D + colg] = z;
            }
        }
    }
}

// ---------------- launch ----------------
extern "C" void kernel_launch(void* const* d_in, const int* in_sizes, int n_in,
                              void* d_out, int out_size, void* d_ws, size_t ws_size,
                              hipStream_t stream)
{
    const float* x      = (const float*)d_in[0];
    const int* seq_src  = (const int*)d_in[1];
    const int* seq_dst  = (const int*)d_in[2];
    const int* knn_src  = (const int*)d_in[3];
    const int* knn_dst  = (const int*)d_in[4];
    const int* dis_src  = (const int*)d_in[5];
    const int* dis_dst  = (const int*)d_in[6];
    const float* Wrel   = (const float*)d_in[7];   // [3][3][128][128]
    const float* brel   = (const float*)d_in[8];   // [3][3][128]
    const float* Wfc    = (const float*)d_in[9];   // [3][128][128]
    const float* bfc    = (const float*)d_in[10];  // [3][128]
    const float* gma    = (const float*)d_in[11];  // [2][128]
    const float* bta    = (const float*)d_in[12];
    const float* rmean  = (const float*)d_in[13];
    const float* rvar   = (const float*)d_in[14];
    float* out = (float*)d_out;

    const size_t ND = (size_t)N_NODES * D;
    float* ws   = (float*)d_ws;
    float* h0   = ws;                         // N*D
    float* h1   = h0 + ND;                    // N*D
    float* ns_  = h1 + ND;                    // 3*N
    float* nd_  = ns_ + 3 * N_NODES;          // 3*N
    float* bvec = nd_ + 3 * N_NODES;          // 3*128
    __bf16* Whi = (__bf16*)(bvec + 3 * D);    // 9*128*128
    __bf16* Wlo = Whi + (size_t)9 * D * D;
    int* outdeg = (int*)(Wlo + (size_t)9 * D * D);   // 3*N
    int* indeg  = outdeg + 3 * N_NODES;               // 3*N
    int* rowptr = indeg + 3 * N_NODES;                // 3*RPS
    int* cursor = rowptr + 3 * RPS;                   // 3*N
    int* bsum   = cursor + 3 * N_NODES;               // 3*SCAN_BLOCKS
    int2* eint  = (int2*)(bsum + 3 * SCAN_BLOCKS + 2); // 3*E {src, w} (8B aligned)

    // ---- graph preprocessing ----
    hipMemsetAsync(outdeg, 0, (size_t)6 * N_NODES * sizeof(int), stream);
    hist_kernel<<<dim3((E_EDGES / 4 + 255) / 256, 3), 256, 0, stream>>>(
        seq_src, seq_dst, knn_src, knn_dst, dis_src, dis_dst, outdeg, indeg);
    scan_part_kernel<<<dim3(SCAN_BLOCKS, 3), 256, 0, stream>>>(indeg, rowptr, bsum);
    scan_mid_kernel<<<1, 256, 0, stream>>>(bsum, rowptr);
    scan_add_kernel<<<dim3(SCAN_BLOCKS, 3), 256, 0, stream>>>(
        rowptr, bsum, cursor, outdeg, indeg, ns_, nd_);
    fill_kernel<<<dim3((E_EDGES + 255) / 256, 3), 256, 0, stream>>>(
        seq_src, seq_dst, knn_src, knn_dst, dis_src, dis_dst, ns_, cursor, eint);

    // ---- weight/bias precompute ----
    wprep_kernel<<<dim3(9, 8), 256, 0, stream>>>(Wrel, Wfc, gma, rvar, Whi, Wlo);
    bias_prep_kernel<<<3, 128, 0, stream>>>(brel, Wfc, bfc, gma, bta, rmean, rvar, bvec);

    // ---- layers (fully fused) ----
    const int GB = (N_NODES + 127) / 128;   // 782
    fused_layer_kernel<<<GB, 512, 0, stream>>>(
        x, rowptr, eint, nd_, Whi, Wlo, h0, bvec, 1);
    fused_layer_kernel<<<GB, 512, 0, stream>>>(
        h0, rowptr, eint, nd_, Whi + (size_t)3 * D * D, Wlo + (size_t)3 * D * D,
        h1, bvec + D, 1);
    fused_layer_kernel<<<GB, 512, 0, stream>>>(
        h1, rowptr, eint, nd_, Whi + (size_t)6 * D * D, Wlo + (size_t)6 * D * D,
        out, bvec + 2 * D, 0);
}

// Round 14
// 994.211 us; speedup vs baseline: 1.1000x; 1.0077x over previous
//
#include <hip/hip_runtime.h>
#include <math.h>

#define N_NODES 100000
#define D 128
#define E_EDGES 600000
#define BN_EPS 1e-5f
#define RPS (N_NODES + 4)                 // padded rowptr stride per relation
#define N4V (N_NODES / 4)                 // 25000 int4 elements
#define SCAN_BLOCKS ((N4V + 255) / 256)   // 98

typedef __attribute__((ext_vector_type(8))) __bf16 bf16x8;
typedef __attribute__((ext_vector_type(4))) __bf16 bf16x4;
typedef __attribute__((ext_vector_type(16))) float f32x16;
typedef __attribute__((ext_vector_type(4))) float f32x4;

// A-tile swizzle: full 4-bit XOR
__device__ __forceinline__ int qswz(int row, int q) { return q ^ (row & 15); }
// B-tile chunk swizzle
__device__ __forceinline__ int swz(int row, int c) { return c ^ ((row >> 1) & 3); }

// ---------------- degree histogram (all 3 relations, 4 edges/thread) ----------------
__global__ __launch_bounds__(256) void hist_kernel(
    const int* __restrict__ s0, const int* __restrict__ d0,
    const int* __restrict__ s1, const int* __restrict__ d1,
    const int* __restrict__ s2, const int* __restrict__ d2,
    int* __restrict__ outdeg, int* __restrict__ indeg)
{
    const int r = blockIdx.y;
    const int* src = (r == 0) ? s0 : ((r == 1) ? s1 : s2);
    const int* dst = (r == 0) ? d0 : ((r == 1) ? d1 : d2);
    int* od = outdeg + (size_t)r * N_NODES;
    int* id = indeg + (size_t)r * N_NODES;
    int i4 = blockIdx.x * 256 + threadIdx.x;
    if (i4 < E_EDGES / 4) {
        int4 s = ((const int4*)src)[i4];
        int4 d = ((const int4*)dst)[i4];
        atomicAdd(&od[s.x], 1); atomicAdd(&od[s.y], 1);
        atomicAdd(&od[s.z], 1); atomicAdd(&od[s.w], 1);
        atomicAdd(&id[d.x], 1); atomicAdd(&id[d.y], 1);
        atomicAdd(&id[d.z], 1); atomicAdd(&id[d.w], 1);
    }
}

// ---------------- parallel scan pass 1 ----------------
__global__ __launch_bounds__(256) void scan_part_kernel(
    const int* __restrict__ indeg, int* __restrict__ rowptr, int* __restrict__ bsum)
{
    const int r = blockIdx.y;
    const int t = threadIdx.x;
    const int lane = t & 63, wid = t >> 6;
    __shared__ int wsum[4], woff[4];
    int i4 = blockIdx.x * 256 + t;
    int4 v = (i4 < N4V) ? ((const int4*)(indeg + (size_t)r * N_NODES))[i4]
                        : make_int4(0, 0, 0, 0);
    int s0 = v.x, s1 = s0 + v.y, s2 = s1 + v.z, s3 = s2 + v.w;
    int x = s3;
    #pragma unroll
    for (int off = 1; off < 64; off <<= 1) {
        int y = __shfl_up(x, off);
        if (lane >= off) x += y;
    }
    if (lane == 63) wsum[wid] = x;
    __syncthreads();
    if (t < 4) { int s = 0; for (int j = 0; j < t; ++j) s += wsum[j]; woff[t] = s; }
    __syncthreads();
    int base = woff[wid] + (x - s3);
    if (i4 < N4V) {
        int idx = i4 * 4;
        int* rp = rowptr + (size_t)r * RPS;
        rp[idx] = base; rp[idx + 1] = base + s0; rp[idx + 2] = base + s1; rp[idx + 3] = base + s2;
    }
    if (t == 255) bsum[r * SCAN_BLOCKS + blockIdx.x] = woff[3] + wsum[3];
}

// ---------------- scan pass 2 ----------------
__global__ __launch_bounds__(256) void scan_mid_kernel(
    int* __restrict__ bsum, int* __restrict__ rowptr)
{
    const int t = threadIdx.x;
    const int lane = t & 63, wid = t >> 6;
    if (wid >= 3) return;
    const int r = wid;
    int carry = 0;
    for (int c = 0; c < (SCAN_BLOCKS + 63) / 64; ++c) {
        int idx = c * 64 + lane;
        int v = (idx < SCAN_BLOCKS) ? bsum[r * SCAN_BLOCKS + idx] : 0;
        int x = v;
        #pragma unroll
        for (int off = 1; off < 64; off <<= 1) {
            int y = __shfl_up(x, off);
            if (lane >= off) x += y;
        }
        if (idx < SCAN_BLOCKS) bsum[r * SCAN_BLOCKS + idx] = carry + x - v;
        carry += __shfl(x, 63);
    }
    if (lane == 0) rowptr[(size_t)r * RPS + N_NODES] = carry;
}

// ---------------- scan pass 3: add offsets, cursor copy, fused norms ----------------
__global__ __launch_bounds__(256) void scan_add_kernel(
    int* __restrict__ rowptr, const int* __restrict__ bsum, int* __restrict__ cursor,
    const int* __restrict__ outdeg, const int* __restrict__ indeg,
    float* __restrict__ ns, float* __restrict__ nd)
{
    const int r = blockIdx.y;
    int i4 = blockIdx.x * 256 + threadIdx.x;
    if (i4 < N4V) {
        int off = bsum[r * SCAN_BLOCKS + blockIdx.x];
        int4* rp4 = (int4*)(rowptr + (size_t)r * RPS);
        int4 v = rp4[i4];
        v.x += off; v.y += off; v.z += off; v.w += off;
        rp4[i4] = v;
        ((int4*)(cursor + (size_t)r * N_NODES))[i4] = v;
        int4 od = ((const int4*)(outdeg + (size_t)r * N_NODES))[i4];
        int4 id = ((const int4*)(indeg + (size_t)r * N_NODES))[i4];
        float4 nsv, ndv;
        nsv.x = rsqrtf((float)(od.x < 1 ? 1 : od.x));
        nsv.y = rsqrtf((float)(od.y < 1 ? 1 : od.y));
        nsv.z = rsqrtf((float)(od.z < 1 ? 1 : od.z));
        nsv.w = rsqrtf((float)(od.w < 1 ? 1 : od.w));
        ndv.x = rsqrtf((float)(id.x < 1 ? 1 : id.x));
        ndv.y = rsqrtf((float)(id.y < 1 ? 1 : id.y));
        ndv.z = rsqrtf((float)(id.z < 1 ? 1 : id.z));
        ndv.w = rsqrtf((float)(id.w < 1 ? 1 : id.w));
        ((float4*)(ns + (size_t)r * N_NODES))[i4] = nsv;
        ((float4*)(nd + (size_t)r * N_NODES))[i4] = ndv;
    }
}

// ---------------- CSR fill: edge record {src, ns[src]} ----------------
__global__ __launch_bounds__(256) void fill_kernel(
    const int* __restrict__ s0, const int* __restrict__ d0,
    const int* __restrict__ s1, const int* __restrict__ d1,
    const int* __restrict__ s2, const int* __restrict__ d2,
    const float* __restrict__ nsv,
    int* __restrict__ cursor, int2* __restrict__ eint)
{
    const int r = blockIdx.y;
    const int* src = (r == 0) ? s0 : ((r == 1) ? s1 : s2);
    const int* dst = (r == 0) ? d0 : ((r == 1) ? d1 : d2);
    int* cur = cursor + (size_t)r * N_NODES;
    int2* eg = eint + (size_t)r * E_EDGES;
    const float* ns_ = nsv + (size_t)r * N_NODES;
    int i = blockIdx.x * 256 + threadIdx.x;
    if (i < E_EDGES) {
        int s = src[i];
        int d = dst[i];
        int pos = atomicAdd(&cur[d], 1);
        eg[pos] = make_int2(s, __float_as_int(ns_[s]));
    }
}

// ---------------- W' precompute: grid (9, 8); 16 k-rows x 128 cols each ----------------
__global__ __launch_bounds__(256) void wprep_kernel(
    const float* __restrict__ Wrel, const float* __restrict__ Wfc,
    const float* __restrict__ gma, const float* __restrict__ rvar,
    __bf16* __restrict__ Whi, __bf16* __restrict__ Wlo)
{
    __shared__ float W2[128][132];
    __shared__ float W1p[16][132];
    const int b = blockIdx.x;   // l*3+r
    const int l = b / 3;
    const int by = blockIdx.y;  // k-row chunk
    const int t = threadIdx.x;

    const float* src1 = Wrel + (size_t)b * D * D;
    const float* src2 = Wfc + (size_t)l * D * D;
    #pragma unroll
    for (int p = 0; p < 16; ++p) {
        int u = t + p * 256;
        int r = u >> 5, f = u & 31;
        *(float4*)&W2[r][f * 4] = *(const float4*)(src2 + r * D + f * 4);
    }
    #pragma unroll
    for (int p = 0; p < 2; ++p) {
        int u = t + p * 256;
        int r = u >> 5, f = u & 31;
        *(float4*)&W1p[r][f * 4] = *(const float4*)(src1 + (size_t)(by * 16 + r) * D + f * 4);
    }
    __syncthreads();

    const int rl = t >> 4;
    const int cb = (t & 15) * 8;
    float acc[8];
    #pragma unroll
    for (int j = 0; j < 8; ++j) acc[j] = 0.f;
    for (int k = 0; k < 128; ++k) {
        float a = W1p[rl][k];
        #pragma unroll
        for (int j = 0; j < 8; ++j) acc[j] = fmaf(a, W2[k][cb + j], acc[j]);
    }
    const int row = by * 16 + rl;
    #pragma unroll
    for (int j = 0; j < 8; ++j) {
        int colj = cb + j;
        float s = 1.0f;
        if (l < 2) s = gma[l * D + colj] * rsqrtf(rvar[l * D + colj] + BN_EPS);
        float v = acc[j] * s;
        __bf16 hb = (__bf16)v;
        __bf16 lb = (__bf16)(v - (float)hb);
        Whi[((size_t)b * D + colj) * D + row] = hb;
        Wlo[((size_t)b * D + colj) * D + row] = lb;
    }
}

// ---------------- bias precompute ----------------
__global__ __launch_bounds__(128) void bias_prep_kernel(
    const float* __restrict__ brel, const float* __restrict__ Wfc,
    const float* __restrict__ bfc,
    const float* __restrict__ gma, const float* __restrict__ bta,
    const float* __restrict__ rmean, const float* __restrict__ rvar,
    float* __restrict__ bvec)
{
    int j = threadIdx.x;
    int l = blockIdx.x;
    float acc = bfc[l * D + j];
    for (int k = 0; k < D; ++k) {
        float bs = brel[(l * 3 + 0) * D + k] + brel[(l * 3 + 1) * D + k] + brel[(l * 3 + 2) * D + k];
        acc = fmaf(bs, Wfc[((size_t)l * D + k) * D + j], acc);
    }
    if (l < 2) {
        float s = gma[l * D + j] * rsqrtf(rvar[l * D + j] + BN_EPS);
        acc = acc * s + (bta[l * D + j] - rmean[l * D + j] * s);
    }
    bvec[l * D + j] = acc;
}

// 16 FMAs of one edge's 4 vec4 into accumulators a0..a3 (ext_vector .x access ok)
#define FMA16(W_, P_, Q_, R_, S_)                                              \
    a0.x = fmaf(W_, P_.x, a0.x); a0.y = fmaf(W_, P_.y, a0.y);                  \
    a0.z = fmaf(W_, P_.z, a0.z); a0.w = fmaf(W_, P_.w, a0.w);                  \
    a1.x = fmaf(W_, Q_.x, a1.x); a1.y = fmaf(W_, Q_.y, a1.y);                  \
    a1.z = fmaf(W_, Q_.z, a1.z); a1.w = fmaf(W_, Q_.w, a1.w);                  \
    a2.x = fmaf(W_, R_.x, a2.x); a2.y = fmaf(W_, R_.y, a2.y);                  \
    a2.z = fmaf(W_, R_.z, a2.z); a2.w = fmaf(W_, R_.w, a2.w);                  \
    a3.x = fmaf(W_, S_.x, a3.x); a3.y = fmaf(W_, S_.y, a3.y);                  \
    a3.z = fmaf(W_, S_.z, a3.z); a3.w = fmaf(W_, S_.w, a3.w);

// async asm load: 4 x dwordx4 from one edge base pointer (offsets 0/128/256/384 bytes).
// volatile, NO memory clobber: value-producing black box, no compiler waitcnt injected.
#define ALOAD4(B_, V0_, V1_, V2_, V3_)                                         \
    asm volatile("global_load_dwordx4 %0, %1, off"            : "=&v"(V0_) : "v"(B_)); \
    asm volatile("global_load_dwordx4 %0, %1, off offset:128" : "=&v"(V1_) : "v"(B_)); \
    asm volatile("global_load_dwordx4 %0, %1, off offset:256" : "=&v"(V2_) : "v"(B_)); \
    asm volatile("global_load_dwordx4 %0, %1, off offset:384" : "=&v"(V3_) : "v"(B_));

// ---------------- fused layer: gather (asm 16-deep burst) -> bf16 hi/lo LDS -> MFMA vs W' ----------------
// BM=128 rows/block, 512 threads = 8 waves; wave w: rows (w&3)*32..+31, cols (w>>2)*64..+63.
// LDS 80 KB -> 2 blocks/CU. Gather: 8-lane groups, 2 rows each, 4-edge asm burst
// (16 dwordx4 forced in flight; manual vmcnt(0) + sched_barrier fences; launch_bounds(512,4)=128 VGPR).
__global__ __launch_bounds__(512, 4) void fused_layer_kernel(
    const float* __restrict__ h,
    const int* __restrict__ rowptr,   // [3][RPS]
    const int2* __restrict__ eint,    // [3][E] {src, ns[src]}
    const float* __restrict__ ndv,    // [3][N]
    const __bf16* __restrict__ Whi,   // [3][col][k], this layer
    const __bf16* __restrict__ Wlo,
    float* __restrict__ out, const float* __restrict__ bias, int relu)
{
    __shared__ __bf16 Ah[128 * 128];   // 32 KB
    __shared__ __bf16 Al[128 * 128];   // 32 KB
    __shared__ __bf16 Bh[128 * 32];    // 8 KB
    __shared__ __bf16 Bl[128 * 32];    // 8 KB

    const int t = threadIdx.x;
    const int lane = t & 63;
    const int wid = t >> 6;           // 0..7
    const int wrow = wid & 3;         // 32-row quarter
    const int wcol = wid >> 2;        // 64-col half
    const int row0 = blockIdx.x * 128;
    const int g = t >> 3;             // 64 gather groups
    const int gl = t & 7;             // lane in group: k-cols gl*4 + 32*j

    f32x16 acc[2];
    #pragma unroll
    for (int nt = 0; nt < 2; ++nt)
        #pragma unroll
        for (int i = 0; i < 16; ++i) acc[nt][i] = 0.0f;

    for (int r = 0; r < 3; ++r) {
        const int* rp = rowptr + (size_t)r * RPS;
        const int2* eg = eint + (size_t)r * E_EDGES;
        const float* nd_ = ndv + (size_t)r * N_NODES;

        // ---- gather: each 8-lane group accumulates 2 rows, 4-edge asm burst ----
        #pragma unroll
        for (int rr = 0; rr < 2; ++rr) {
            int rowl = g * 2 + rr;
            int grow = row0 + rowl;
            f32x4 a0 = {0,0,0,0}, a1 = {0,0,0,0}, a2 = {0,0,0,0}, a3 = {0,0,0,0};
            if (grow < N_NODES) {
                int beg = rp[grow], end = rp[grow + 1];
                float sc = nd_[grow];
                int e = beg;
                for (; e + 4 <= end; e += 4) {
                    int2 q0 = eg[e], q1 = eg[e + 1], q2 = eg[e + 2], q3 = eg[e + 3];
                    const float* p0 = h + (size_t)q0.x * D + gl * 4;
                    const float* p1 = h + (size_t)q1.x * D + gl * 4;
                    const float* p2 = h + (size_t)q2.x * D + gl * 4;
                    const float* p3 = h + (size_t)q3.x * D + gl * 4;
                    f32x4 u00, u01, u02, u03, u10, u11, u12, u13;
                    f32x4 u20, u21, u22, u23, u30, u31, u32, u33;
                    ALOAD4(p0, u00, u01, u02, u03);
                    ALOAD4(p1, u10, u11, u12, u13);
                    ALOAD4(p2, u20, u21, u22, u23);
                    ALOAD4(p3, u30, u31, u32, u33);
                    __builtin_amdgcn_sched_barrier(0);
                    asm volatile("s_waitcnt vmcnt(0)" ::: "memory");
                    __builtin_amdgcn_sched_barrier(0);
                    float wa = __int_as_float(q0.y), wb = __int_as_float(q1.y);
                    float wc = __int_as_float(q2.y), wd = __int_as_float(q3.y);
                    FMA16(wa, u00, u01, u02, u03);
                    FMA16(wb, u10, u11, u12, u13);
                    FMA16(wc, u20, u21, u22, u23);
                    FMA16(wd, u30, u31, u32, u33);
                }
                if (e + 2 <= end) {
                    int2 q0 = eg[e], q1 = eg[e + 1];
                    const float* p0 = h + (size_t)q0.x * D + gl * 4;
                    const float* p1 = h + (size_t)q1.x * D + gl * 4;
                    f32x4 u00 = *(const f32x4*)(p0),      u01 = *(const f32x4*)(p0 + 32);
                    f32x4 u02 = *(const f32x4*)(p0 + 64), u03 = *(const f32x4*)(p0 + 96);
                    f32x4 u10 = *(const f32x4*)(p1),      u11 = *(const f32x4*)(p1 + 32);
                    f32x4 u12 = *(const f32x4*)(p1 + 64), u13 = *(const f32x4*)(p1 + 96);
                    float wa = __int_as_float(q0.y), wb = __int_as_float(q1.y);
                    FMA16(wa, u00, u01, u02, u03);
                    FMA16(wb, u10, u11, u12, u13);
                    e += 2;
                }
                if (e < end) {
                    int2 q0 = eg[e];
                    const float* p0 = h + (size_t)q0.x * D + gl * 4;
                    f32x4 u00 = *(const f32x4*)(p0),      u01 = *(const f32x4*)(p0 + 32);
                    f32x4 u02 = *(const f32x4*)(p0 + 64), u03 = *(const f32x4*)(p0 + 96);
                    float wa = __int_as_float(q0.y);
                    FMA16(wa, u00, u01, u02, u03);
                }
                a0.x *= sc; a0.y *= sc; a0.z *= sc; a0.w *= sc;
                a1.x *= sc; a1.y *= sc; a1.z *= sc; a1.w *= sc;
                a2.x *= sc; a2.y *= sc; a2.z *= sc; a2.w *= sc;
                a3.x *= sc; a3.y *= sc; a3.z *= sc; a3.w *= sc;
            }
            f32x4 av[4] = {a0, a1, a2, a3};
            #pragma unroll
            for (int j = 0; j < 4; ++j) {
                int q = (gl >> 1) + 4 * j;
                int idx = rowl * 128 + qswz(rowl, q) * 8 + (gl & 1) * 4;
                bf16x4 hv, lv;
                #pragma unroll
                for (int c = 0; c < 4; ++c) {
                    float val = av[j][c];
                    __bf16 hb = (__bf16)val;
                    hv[c] = hb;
                    lv[c] = (__bf16)(val - (float)hb);
                }
                *(bf16x4*)&Ah[idx] = hv;
                *(bf16x4*)&Al[idx] = lv;
            }
        }

        // ---- MFMA over 4 K-slices ----
        for (int ks = 0; ks < 4; ++ks) {
            // stage B slice: 128 cols x 32 k (hi+lo per thread)
            {
                int colj = t >> 2;
                int c = t & 3;
                int idx = colj * 32 + swz(colj, c) * 8;
                const __bf16* sh = Whi + (size_t)r * D * D + (size_t)colj * D + ks * 32 + c * 8;
                const __bf16* sl = Wlo + (size_t)r * D * D + (size_t)colj * D + ks * 32 + c * 8;
                *(bf16x8*)&Bh[idx] = *(const bf16x8*)sh;
                *(bf16x8*)&Bl[idx] = *(const bf16x8*)sl;
            }
            __syncthreads();   // A-writes (ks==0) and B-writes visible

            const int arow = lane & 31;
            const int kgrp = lane >> 5;
            #pragma unroll
            for (int ksub = 0; ksub < 2; ++ksub) {
                int ac = ksub * 2 + kgrp;
                int arow_g = wrow * 32 + arow;
                int aidx = arow_g * 128 + qswz(arow_g, ks * 4 + ac) * 8;
                bf16x8 ahv = *(const bf16x8*)&Ah[aidx];
                bf16x8 alv = *(const bf16x8*)&Al[aidx];
                #pragma unroll
                for (int nt = 0; nt < 2; ++nt) {
                    int colg = wcol * 64 + nt * 32 + arow;
                    int bidx = colg * 32 + swz(colg, ac) * 8;
                    bf16x8 bhv = *(const bf16x8*)&Bh[bidx];
                    bf16x8 blv = *(const bf16x8*)&Bl[bidx];
                    acc[nt] = __builtin_amdgcn_mfma_f32_32x32x16_bf16(ahv, bhv, acc[nt], 0, 0, 0);
                    acc[nt] = __builtin_amdgcn_mfma_f32_32x32x16_bf16(ahv, blv, acc[nt], 0, 0, 0);
                    acc[nt] = __builtin_amdgcn_mfma_f32_32x32x16_bf16(alv, bhv, acc[nt], 0, 0, 0);
                }
            }
            __syncthreads();   // MFMA reads done before next stage/gather writes
        }
    }

    // ---- epilogue: bias (+ ReLU), single write ----
    const int colb = lane & 31;
    const int rq = lane >> 5;
    #pragma unroll
    for (int nt = 0; nt < 2; ++nt) {
        int colg = wcol * 64 + nt * 32 + colb;
        float bv = bias[colg];
        #pragma unroll
        for (int reg = 0; reg < 16; ++reg) {
            int rowl = wrow * 32 + (reg & 3) + 8 * (reg >> 2) + 4 * rq;
            int grow = row0 + rowl;
            if (grow < N_NODES) {
                float z = acc[nt][reg] + bv;
                if (relu) z = fmaxf(z, 0.f);
                out[(size_t)grow * D + colg] = z;
            }
        }
    }
}

// ---------------- launch ----------------
extern "C" void kernel_launch(void* const* d_in, const int* in_sizes, int n_in,
                              void* d_out, int out_size, void* d_ws, size_t ws_size,
                              hipStream_t stream)
{
    const float* x      = (const float*)d_in[0];
    const int* seq_src  = (const int*)d_in[1];
    const int* seq_dst  = (const int*)d_in[2];
    const int* knn_src  = (const int*)d_in[3];
    const int* knn_dst  = (const int*)d_in[4];
    const int* dis_src  = (const int*)d_in[5];
    const int* dis_dst  = (const int*)d_in[6];
    const float* Wrel   = (const float*)d_in[7];   // [3][3][128][128]
    const float* brel   = (const float*)d_in[8];   // [3][3][128]
    const float* Wfc    = (const float*)d_in[9];   // [3][128][128]
    const float* bfc    = (const float*)d_in[10];  // [3][128]
    const float* gma    = (const float*)d_in[11];  // [2][128]
    const float* bta    = (const float*)d_in[12];
    const float* rmean  = (const float*)d_in[13];
    const float* rvar   = (const float*)d_in[14];
    float* out = (float*)d_out;

    const size_t ND = (size_t)N_NODES * D;
    float* ws   = (float*)d_ws;
    float* h0   = ws;                         // N*D
    float* h1   = h0 + ND;                    // N*D
    float* ns_  = h1 + ND;                    // 3*N
    float* nd_  = ns_ + 3 * N_NODES;          // 3*N
    float* bvec = nd_ + 3 * N_NODES;          // 3*128
    __bf16* Whi = (__bf16*)(bvec + 3 * D);    // 9*128*128
    __bf16* Wlo = Whi + (size_t)9 * D * D;
    int* outdeg = (int*)(Wlo + (size_t)9 * D * D);   // 3*N
    int* indeg  = outdeg + 3 * N_NODES;               // 3*N
    int* rowptr = indeg + 3 * N_NODES;                // 3*RPS
    int* cursor = rowptr + 3 * RPS;                   // 3*N
    int* bsum   = cursor + 3 * N_NODES;               // 3*SCAN_BLOCKS
    int2* eint  = (int2*)(bsum + 3 * SCAN_BLOCKS + 2); // 3*E {src, w} (8B aligned)

    // ---- graph preprocessing ----
    hipMemsetAsync(outdeg, 0, (size_t)6 * N_NODES * sizeof(int), stream);
    hist_kernel<<<dim3((E_EDGES / 4 + 255) / 256, 3), 256, 0, stream>>>(
        seq_src, seq_dst, knn_src, knn_dst, dis_src, dis_dst, outdeg, indeg);
    scan_part_kernel<<<dim3(SCAN_BLOCKS, 3), 256, 0, stream>>>(indeg, rowptr, bsum);
    scan_mid_kernel<<<1, 256, 0, stream>>>(bsum, rowptr);
    scan_add_kernel<<<dim3(SCAN_BLOCKS, 3), 256, 0, stream>>>(
        rowptr, bsum, cursor, outdeg, indeg, ns_, nd_);
    fill_kernel<<<dim3((E_EDGES + 255) / 256, 3), 256, 0, stream>>>(
        seq_src, seq_dst, knn_src, knn_dst, dis_src, dis_dst, ns_, cursor, eint);

    // ---- weight/bias precompute ----
    wprep_kernel<<<dim3(9, 8), 256, 0, stream>>>(Wrel, Wfc, gma, rvar, Whi, Wlo);
    bias_prep_kernel<<<3, 128, 0, stream>>>(brel, Wfc, bfc, gma, bta, rmean, rvar, bvec);

    // ---- layers (fully fused) ----
    const int GB = (N_NODES + 127) / 128;   // 782
    fused_layer_kernel<<<GB, 512, 0, stream>>>(
        x, rowptr, eint, nd_, Whi, Wlo, h0, bvec, 1);
    fused_layer_kernel<<<GB, 512, 0, stream>>>(
        h0, rowptr, eint, nd_, Whi + (size_t)3 * D * D, Wlo + (size_t)3 * D * D,
        h1, bvec + D, 1);
    fused_layer_kernel<<<GB, 512, 0, stream>>>(
        h1, rowptr, eint, nd_, Whi + (size_t)6 * D * D, Wlo + (size_t)6 * D * D,
        out, bvec + 2 * D, 0);
}

// Round 15
// 784.084 us; speedup vs baseline: 1.3948x; 1.2680x over previous
//
#include <hip/hip_runtime.h>
#include <math.h>

#define N_NODES 100000
#define D 128
#define E_EDGES 600000
#define BN_EPS 1e-5f
#define RPS (N_NODES + 4)                 // padded rowptr stride per relation
#define N4V (N_NODES / 4)                 // 25000 int4 elements
#define SCAN_BLOCKS ((N4V + 255) / 256)   // 98

typedef __attribute__((ext_vector_type(8))) __bf16 bf16x8;
typedef __attribute__((ext_vector_type(4))) __bf16 bf16x4;
typedef __attribute__((ext_vector_type(16))) float f32x16;

// A-tile swizzle: full 4-bit XOR (best measured: 3.6M conflicts at BM=128)
__device__ __forceinline__ int qswz(int row, int q) { return q ^ (row & 15); }
// B-tile chunk swizzle
__device__ __forceinline__ int swz(int row, int c) { return c ^ ((row >> 1) & 3); }

// ---------------- degree histogram (all 3 relations, 4 edges/thread) ----------------
__global__ __launch_bounds__(256) void hist_kernel(
    const int* __restrict__ s0, const int* __restrict__ d0,
    const int* __restrict__ s1, const int* __restrict__ d1,
    const int* __restrict__ s2, const int* __restrict__ d2,
    int* __restrict__ outdeg, int* __restrict__ indeg)
{
    const int r = blockIdx.y;
    const int* src = (r == 0) ? s0 : ((r == 1) ? s1 : s2);
    const int* dst = (r == 0) ? d0 : ((r == 1) ? d1 : d2);
    int* od = outdeg + (size_t)r * N_NODES;
    int* id = indeg + (size_t)r * N_NODES;
    int i4 = blockIdx.x * 256 + threadIdx.x;
    if (i4 < E_EDGES / 4) {
        int4 s = ((const int4*)src)[i4];
        int4 d = ((const int4*)dst)[i4];
        atomicAdd(&od[s.x], 1); atomicAdd(&od[s.y], 1);
        atomicAdd(&od[s.z], 1); atomicAdd(&od[s.w], 1);
        atomicAdd(&id[d.x], 1); atomicAdd(&id[d.y], 1);
        atomicAdd(&id[d.z], 1); atomicAdd(&id[d.w], 1);
    }
}

// ---------------- parallel scan pass 1 ----------------
__global__ __launch_bounds__(256) void scan_part_kernel(
    const int* __restrict__ indeg, int* __restrict__ rowptr, int* __restrict__ bsum)
{
    const int r = blockIdx.y;
    const int t = threadIdx.x;
    const int lane = t & 63, wid = t >> 6;
    __shared__ int wsum[4], woff[4];
    int i4 = blockIdx.x * 256 + t;
    int4 v = (i4 < N4V) ? ((const int4*)(indeg + (size_t)r * N_NODES))[i4]
                        : make_int4(0, 0, 0, 0);
    int s0 = v.x, s1 = s0 + v.y, s2 = s1 + v.z, s3 = s2 + v.w;
    int x = s3;
    #pragma unroll
    for (int off = 1; off < 64; off <<= 1) {
        int y = __shfl_up(x, off);
        if (lane >= off) x += y;
    }
    if (lane == 63) wsum[wid] = x;
    __syncthreads();
    if (t < 4) { int s = 0; for (int j = 0; j < t; ++j) s += wsum[j]; woff[t] = s; }
    __syncthreads();
    int base = woff[wid] + (x - s3);
    if (i4 < N4V) {
        int idx = i4 * 4;
        int* rp = rowptr + (size_t)r * RPS;
        rp[idx] = base; rp[idx + 1] = base + s0; rp[idx + 2] = base + s1; rp[idx + 3] = base + s2;
    }
    if (t == 255) bsum[r * SCAN_BLOCKS + blockIdx.x] = woff[3] + wsum[3];
}

// ---------------- scan pass 2 ----------------
__global__ __launch_bounds__(256) void scan_mid_kernel(
    int* __restrict__ bsum, int* __restrict__ rowptr)
{
    const int t = threadIdx.x;
    const int lane = t & 63, wid = t >> 6;
    if (wid >= 3) return;
    const int r = wid;
    int carry = 0;
    for (int c = 0; c < (SCAN_BLOCKS + 63) / 64; ++c) {
        int idx = c * 64 + lane;
        int v = (idx < SCAN_BLOCKS) ? bsum[r * SCAN_BLOCKS + idx] : 0;
        int x = v;
        #pragma unroll
        for (int off = 1; off < 64; off <<= 1) {
            int y = __shfl_up(x, off);
            if (lane >= off) x += y;
        }
        if (idx < SCAN_BLOCKS) bsum[r * SCAN_BLOCKS + idx] = carry + x - v;
        carry += __shfl(x, 63);
    }
    if (lane == 0) rowptr[(size_t)r * RPS + N_NODES] = carry;
}

// ---------------- scan pass 3: add offsets, cursor copy, fused norms ----------------
__global__ __launch_bounds__(256) void scan_add_kernel(
    int* __restrict__ rowptr, const int* __restrict__ bsum, int* __restrict__ cursor,
    const int* __restrict__ outdeg, const int* __restrict__ indeg,
    float* __restrict__ ns, float* __restrict__ nd)
{
    const int r = blockIdx.y;
    int i4 = blockIdx.x * 256 + threadIdx.x;
    if (i4 < N4V) {
        int off = bsum[r * SCAN_BLOCKS + blockIdx.x];
        int4* rp4 = (int4*)(rowptr + (size_t)r * RPS);
        int4 v = rp4[i4];
        v.x += off; v.y += off; v.z += off; v.w += off;
        rp4[i4] = v;
        ((int4*)(cursor + (size_t)r * N_NODES))[i4] = v;
        int4 od = ((const int4*)(outdeg + (size_t)r * N_NODES))[i4];
        int4 id = ((const int4*)(indeg + (size_t)r * N_NODES))[i4];
        float4 nsv, ndv;
        nsv.x = rsqrtf((float)(od.x < 1 ? 1 : od.x));
        nsv.y = rsqrtf((float)(od.y < 1 ? 1 : od.y));
        nsv.z = rsqrtf((float)(od.z < 1 ? 1 : od.z));
        nsv.w = rsqrtf((float)(od.w < 1 ? 1 : od.w));
        ndv.x = rsqrtf((float)(id.x < 1 ? 1 : id.x));
        ndv.y = rsqrtf((float)(id.y < 1 ? 1 : id.y));
        ndv.z = rsqrtf((float)(id.z < 1 ? 1 : id.z));
        ndv.w = rsqrtf((float)(id.w < 1 ? 1 : id.w));
        ((float4*)(ns + (size_t)r * N_NODES))[i4] = nsv;
        ((float4*)(nd + (size_t)r * N_NODES))[i4] = ndv;
    }
}

// ---------------- CSR fill: edge record {src, ns[src]} ----------------
__global__ __launch_bounds__(256) void fill_kernel(
    const int* __restrict__ s0, const int* __restrict__ d0,
    const int* __restrict__ s1, const int* __restrict__ d1,
    const int* __restrict__ s2, const int* __restrict__ d2,
    const float* __restrict__ nsv,
    int* __restrict__ cursor, int2* __restrict__ eint)
{
    const int r = blockIdx.y;
    const int* src = (r == 0) ? s0 : ((r == 1) ? s1 : s2);
    const int* dst = (r == 0) ? d0 : ((r == 1) ? d1 : d2);
    int* cur = cursor + (size_t)r * N_NODES;
    int2* eg = eint + (size_t)r * E_EDGES;
    const float* ns_ = nsv + (size_t)r * N_NODES;
    int i = blockIdx.x * 256 + threadIdx.x;
    if (i < E_EDGES) {
        int s = src[i];
        int d = dst[i];
        int pos = atomicAdd(&cur[d], 1);
        eg[pos] = make_int2(s, __float_as_int(ns_[s]));
    }
}

// ---------------- W' precompute: grid (9, 8); block computes 16 k-rows x 128 cols ----------------
__global__ __launch_bounds__(256) void wprep_kernel(
    const float* __restrict__ Wrel, const float* __restrict__ Wfc,
    const float* __restrict__ gma, const float* __restrict__ rvar,
    __bf16* __restrict__ Whi, __bf16* __restrict__ Wlo)
{
    __shared__ float W2[128][132];
    __shared__ float W1p[16][132];
    const int b = blockIdx.x;   // l*3+r
    const int l = b / 3;
    const int by = blockIdx.y;  // k-row chunk
    const int t = threadIdx.x;

    const float* src1 = Wrel + (size_t)b * D * D;   // [k][j]
    const float* src2 = Wfc + (size_t)l * D * D;
    #pragma unroll
    for (int p = 0; p < 16; ++p) {
        int u = t + p * 256;
        int r = u >> 5, f = u & 31;
        *(float4*)&W2[r][f * 4] = *(const float4*)(src2 + r * D + f * 4);
    }
    #pragma unroll
    for (int p = 0; p < 2; ++p) {
        int u = t + p * 256;
        int r = u >> 5, f = u & 31;
        *(float4*)&W1p[r][f * 4] = *(const float4*)(src1 + (size_t)(by * 16 + r) * D + f * 4);
    }
    __syncthreads();

    const int rl = t >> 4;          // 0..15 local k-row
    const int cb = (t & 15) * 8;    // 8 cols
    float acc[8];
    #pragma unroll
    for (int j = 0; j < 8; ++j) acc[j] = 0.f;
    for (int k = 0; k < 128; ++k) {
        float a = W1p[rl][k];
        #pragma unroll
        for (int j = 0; j < 8; ++j) acc[j] = fmaf(a, W2[k][cb + j], acc[j]);
    }
    const int row = by * 16 + rl;
    #pragma unroll
    for (int j = 0; j < 8; ++j) {
        int colj = cb + j;
        float s = 1.0f;
        if (l < 2) s = gma[l * D + colj] * rsqrtf(rvar[l * D + colj] + BN_EPS);
        float v = acc[j] * s;
        __bf16 hb = (__bf16)v;
        __bf16 lb = (__bf16)(v - (float)hb);
        Whi[((size_t)b * D + colj) * D + row] = hb;
        Wlo[((size_t)b * D + colj) * D + row] = lb;
    }
}

// ---------------- bias precompute ----------------
__global__ __launch_bounds__(128) void bias_prep_kernel(
    const float* __restrict__ brel, const float* __restrict__ Wfc,
    const float* __restrict__ bfc,
    const float* __restrict__ gma, const float* __restrict__ bta,
    const float* __restrict__ rmean, const float* __restrict__ rvar,
    float* __restrict__ bvec)
{
    int j = threadIdx.x;
    int l = blockIdx.x;
    float acc = bfc[l * D + j];
    for (int k = 0; k < D; ++k) {
        float bs = brel[(l * 3 + 0) * D + k] + brel[(l * 3 + 1) * D + k] + brel[(l * 3 + 2) * D + k];
        acc = fmaf(bs, Wfc[((size_t)l * D + k) * D + j], acc);
    }
    if (l < 2) {
        float s = gma[l * D + j] * rsqrtf(rvar[l * D + j] + BN_EPS);
        acc = acc * s + (bta[l * D + j] - rmean[l * D + j] * s);
    }
    bvec[l * D + j] = acc;
}

// 16 FMAs of one edge's 4 float4 into the row accumulators a0..a3
#define FMA16(W_, P_, Q_, R_, S_)                                              \
    a0.x = fmaf(W_, P_.x, a0.x); a0.y = fmaf(W_, P_.y, a0.y);                  \
    a0.z = fmaf(W_, P_.z, a0.z); a0.w = fmaf(W_, P_.w, a0.w);                  \
    a1.x = fmaf(W_, Q_.x, a1.x); a1.y = fmaf(W_, Q_.y, a1.y);                  \
    a1.z = fmaf(W_, Q_.z, a1.z); a1.w = fmaf(W_, Q_.w, a1.w);                  \
    a2.x = fmaf(W_, R_.x, a2.x); a2.y = fmaf(W_, R_.y, a2.y);                  \
    a2.z = fmaf(W_, R_.z, a2.z); a2.w = fmaf(W_, R_.w, a2.w);                  \
    a3.x = fmaf(W_, S_.x, a3.x); a3.y = fmaf(W_, S_.y, a3.y);                  \
    a3.z = fmaf(W_, S_.z, a3.z); a3.w = fmaf(W_, S_.w, a3.w);

// ---------------- fused layer: gather -> bf16 hi/lo LDS -> MFMA vs W' (3 relations) ----------------
// BM=128 rows/block, 512 threads = 8 waves; wave w: rows (w&3)*32..+31, cols (w>>2)*64..+63.
// LDS 80 KB -> 2 blocks/CU. Gather: 8-lane groups, 2 rows each, 4-edge burst
// (4 float4/lane/edge; launch_bounds(512,4)). R10-proven configuration.
__global__ __launch_bounds__(512, 4) void fused_layer_kernel(
    const float* __restrict__ h,
    const int* __restrict__ rowptr,   // [3][RPS]
    const int2* __restrict__ eint,    // [3][E] {src, ns[src]}
    const float* __restrict__ ndv,    // [3][N]
    const __bf16* __restrict__ Whi,   // [3][col][k], this layer
    const __bf16* __restrict__ Wlo,
    float* __restrict__ out, const float* __restrict__ bias, int relu)
{
    __shared__ __bf16 Ah[128 * 128];   // 32 KB
    __shared__ __bf16 Al[128 * 128];   // 32 KB
    __shared__ __bf16 Bh[128 * 32];    // 8 KB
    __shared__ __bf16 Bl[128 * 32];    // 8 KB

    const int t = threadIdx.x;
    const int lane = t & 63;
    const int wid = t >> 6;           // 0..7
    const int wrow = wid & 3;         // 32-row quarter
    const int wcol = wid >> 2;        // 64-col half
    const int row0 = blockIdx.x * 128;
    const int g = t >> 3;             // 64 gather groups
    const int gl = t & 7;             // lane in group: k-cols gl*4 + 32*j

    f32x16 acc[2];
    #pragma unroll
    for (int nt = 0; nt < 2; ++nt)
        #pragma unroll
        for (int i = 0; i < 16; ++i) acc[nt][i] = 0.0f;

    for (int r = 0; r < 3; ++r) {
        const int* rp = rowptr + (size_t)r * RPS;
        const int2* eg = eint + (size_t)r * E_EDGES;
        const float* nd_ = ndv + (size_t)r * N_NODES;

        // ---- gather: each 8-lane group accumulates 2 rows, 4-edge unroll ----
        #pragma unroll
        for (int rr = 0; rr < 2; ++rr) {
            int rowl = g * 2 + rr;
            int grow = row0 + rowl;
            float4 a0 = {0,0,0,0}, a1 = {0,0,0,0}, a2 = {0,0,0,0}, a3 = {0,0,0,0};
            if (grow < N_NODES) {
                int beg = rp[grow], end = rp[grow + 1];
                float sc = nd_[grow];
                int e = beg;
                for (; e + 4 <= end; e += 4) {
                    int2 q0 = eg[e], q1 = eg[e + 1], q2 = eg[e + 2], q3 = eg[e + 3];
                    const float* p0 = h + (size_t)q0.x * D + gl * 4;
                    const float* p1 = h + (size_t)q1.x * D + gl * 4;
                    const float* p2 = h + (size_t)q2.x * D + gl * 4;
                    const float* p3 = h + (size_t)q3.x * D + gl * 4;
                    float4 u00 = *(const float4*)(p0),      u01 = *(const float4*)(p0 + 32);
                    float4 u02 = *(const float4*)(p0 + 64), u03 = *(const float4*)(p0 + 96);
                    float4 u10 = *(const float4*)(p1),      u11 = *(const float4*)(p1 + 32);
                    float4 u12 = *(const float4*)(p1 + 64), u13 = *(const float4*)(p1 + 96);
                    float4 u20 = *(const float4*)(p2),      u21 = *(const float4*)(p2 + 32);
                    float4 u22 = *(const float4*)(p2 + 64), u23 = *(const float4*)(p2 + 96);
                    float4 u30 = *(const float4*)(p3),      u31 = *(const float4*)(p3 + 32);
                    float4 u32 = *(const float4*)(p3 + 64), u33 = *(const float4*)(p3 + 96);
                    float wa = __int_as_float(q0.y), wb = __int_as_float(q1.y);
                    float wc = __int_as_float(q2.y), wd = __int_as_float(q3.y);
                    FMA16(wa, u00, u01, u02, u03);
                    FMA16(wb, u10, u11, u12, u13);
                    FMA16(wc, u20, u21, u22, u23);
                    FMA16(wd, u30, u31, u32, u33);
                }
                if (e + 2 <= end) {
                    int2 q0 = eg[e], q1 = eg[e + 1];
                    const float* p0 = h + (size_t)q0.x * D + gl * 4;
                    const float* p1 = h + (size_t)q1.x * D + gl * 4;
                    float4 u00 = *(const float4*)(p0),      u01 = *(const float4*)(p0 + 32);
                    float4 u02 = *(const float4*)(p0 + 64), u03 = *(const float4*)(p0 + 96);
                    float4 u10 = *(const float4*)(p1),      u11 = *(const float4*)(p1 + 32);
                    float4 u12 = *(const float4*)(p1 + 64), u13 = *(const float4*)(p1 + 96);
                    float wa = __int_as_float(q0.y), wb = __int_as_float(q1.y);
                    FMA16(wa, u00, u01, u02, u03);
                    FMA16(wb, u10, u11, u12, u13);
                    e += 2;
                }
                if (e < end) {
                    int2 q0 = eg[e];
                    const float* p0 = h + (size_t)q0.x * D + gl * 4;
                    float4 u00 = *(const float4*)(p0),      u01 = *(const float4*)(p0 + 32);
                    float4 u02 = *(const float4*)(p0 + 64), u03 = *(const float4*)(p0 + 96);
                    float wa = __int_as_float(q0.y);
                    FMA16(wa, u00, u01, u02, u03);
                }
                a0.x *= sc; a0.y *= sc; a0.z *= sc; a0.w *= sc;
                a1.x *= sc; a1.y *= sc; a1.z *= sc; a1.w *= sc;
                a2.x *= sc; a2.y *= sc; a2.z *= sc; a2.w *= sc;
                a3.x *= sc; a3.y *= sc; a3.z *= sc; a3.w *= sc;
            }
            float4 av[4] = {a0, a1, a2, a3};
            #pragma unroll
            for (int j = 0; j < 4; ++j) {
                int q = (gl >> 1) + 4 * j;
                int idx = rowl * 128 + qswz(rowl, q) * 8 + (gl & 1) * 4;
                bf16x4 hv, lv;
                float* ap = &av[j].x;
                #pragma unroll
                for (int c = 0; c < 4; ++c) {
                    __bf16 hb = (__bf16)ap[c];
                    hv[c] = hb;
                    lv[c] = (__bf16)(ap[c] - (float)hb);
                }
                *(bf16x4*)&Ah[idx] = hv;
                *(bf16x4*)&Al[idx] = lv;
            }
        }

        // ---- MFMA over 4 K-slices ----
        for (int ks = 0; ks < 4; ++ks) {
            // stage B slice: 128 cols x 32 k (hi+lo per thread)
            {
                int colj = t >> 2;
                int c = t & 3;
                int idx = colj * 32 + swz(colj, c) * 8;
                const __bf16* sh = Whi + (size_t)r * D * D + (size_t)colj * D + ks * 32 + c * 8;
                const __bf16* sl = Wlo + (size_t)r * D * D + (size_t)colj * D + ks * 32 + c * 8;
                *(bf16x8*)&Bh[idx] = *(const bf16x8*)sh;
                *(bf16x8*)&Bl[idx] = *(const bf16x8*)sl;
            }
            __syncthreads();   // A-writes (ks==0) and B-writes visible

            const int arow = lane & 31;
            const int kgrp = lane >> 5;
            #pragma unroll
            for (int ksub = 0; ksub < 2; ++ksub) {
                int ac = ksub * 2 + kgrp;
                int arow_g = wrow * 32 + arow;
                int aidx = arow_g * 128 + qswz(arow_g, ks * 4 + ac) * 8;
                bf16x8 ahv = *(const bf16x8*)&Ah[aidx];
                bf16x8 alv = *(const bf16x8*)&Al[aidx];
                #pragma unroll
                for (int nt = 0; nt < 2; ++nt) {
                    int colg = wcol * 64 + nt * 32 + arow;
                    int bidx = colg * 32 + swz(colg, ac) * 8;
                    bf16x8 bhv = *(const bf16x8*)&Bh[bidx];
                    bf16x8 blv = *(const bf16x8*)&Bl[bidx];
                    acc[nt] = __builtin_amdgcn_mfma_f32_32x32x16_bf16(ahv, bhv, acc[nt], 0, 0, 0);
                    acc[nt] = __builtin_amdgcn_mfma_f32_32x32x16_bf16(ahv, blv, acc[nt], 0, 0, 0);
                    acc[nt] = __builtin_amdgcn_mfma_f32_32x32x16_bf16(alv, bhv, acc[nt], 0, 0, 0);
                }
            }
            __syncthreads();   // MFMA reads done before next stage/gather writes
        }
    }

    // ---- epilogue: bias (+ ReLU), single write ----
    const int colb = lane & 31;
    const int rq = lane >> 5;
    #pragma unroll
    for (int nt = 0; nt < 2; ++nt) {
        int colg = wcol * 64 + nt * 32 + colb;
        float bv = bias[colg];
        #pragma unroll
        for (int reg = 0; reg < 16; ++reg) {
            int rowl = wrow * 32 + (reg & 3) + 8 * (reg >> 2) + 4 * rq;
            int grow = row0 + rowl;
            if (grow < N_NODES) {
                float z = acc[nt][reg] + bv;
                if (relu) z = fmaxf(z, 0.f);
                out[(size_t)grow * D + colg] = z;
            }
        }
    }
}

// ---------------- launch ----------------
extern "C" void kernel_launch(void* const* d_in, const int* in_sizes, int n_in,
                              void* d_out, int out_size, void* d_ws, size_t ws_size,
                              hipStream_t stream)
{
    const float* x      = (const float*)d_in[0];
    const int* seq_src  = (const int*)d_in[1];
    const int* seq_dst  = (const int*)d_in[2];
    const int* knn_src  = (const int*)d_in[3];
    const int* knn_dst  = (const int*)d_in[4];
    const int* dis_src  = (const int*)d_in[5];
    const int* dis_dst  = (const int*)d_in[6];
    const float* Wrel   = (const float*)d_in[7];   // [3][3][128][128]
    const float* brel   = (const float*)d_in[8];   // [3][3][128]
    const float* Wfc    = (const float*)d_in[9];   // [3][128][128]
    const float* bfc    = (const float*)d_in[10];  // [3][128]
    const float* gma    = (const float*)d_in[11];  // [2][128]
    const float* bta    = (const float*)d_in[12];
    const float* rmean  = (const float*)d_in[13];
    const float* rvar   = (const float*)d_in[14];
    float* out = (float*)d_out;

    const size_t ND = (size_t)N_NODES * D;
    float* ws   = (float*)d_ws;
    float* h0   = ws;                         // N*D
    float* h1   = h0 + ND;                    // N*D
    float* ns_  = h1 + ND;                    // 3*N
    float* nd_  = ns_ + 3 * N_NODES;          // 3*N
    float* bvec = nd_ + 3 * N_NODES;          // 3*128
    __bf16* Whi = (__bf16*)(bvec + 3 * D);    // 9*128*128
    __bf16* Wlo = Whi + (size_t)9 * D * D;
    int* outdeg = (int*)(Wlo + (size_t)9 * D * D);   // 3*N
    int* indeg  = outdeg + 3 * N_NODES;               // 3*N
    int* rowptr = indeg + 3 * N_NODES;                // 3*RPS
    int* cursor = rowptr + 3 * RPS;                   // 3*N
    int* bsum   = cursor + 3 * N_NODES;               // 3*SCAN_BLOCKS
    int2* eint  = (int2*)(bsum + 3 * SCAN_BLOCKS + 2); // 3*E {src, w} (8B aligned)

    // ---- graph preprocessing ----
    hipMemsetAsync(outdeg, 0, (size_t)6 * N_NODES * sizeof(int), stream);
    hist_kernel<<<dim3((E_EDGES / 4 + 255) / 256, 3), 256, 0, stream>>>(
        seq_src, seq_dst, knn_src, knn_dst, dis_src, dis_dst, outdeg, indeg);
    scan_part_kernel<<<dim3(SCAN_BLOCKS, 3), 256, 0, stream>>>(indeg, rowptr, bsum);
    scan_mid_kernel<<<1, 256, 0, stream>>>(bsum, rowptr);
    scan_add_kernel<<<dim3(SCAN_BLOCKS, 3), 256, 0, stream>>>(
        rowptr, bsum, cursor, outdeg, indeg, ns_, nd_);
    fill_kernel<<<dim3((E_EDGES + 255) / 256, 3), 256, 0, stream>>>(
        seq_src, seq_dst, knn_src, knn_dst, dis_src, dis_dst, ns_, cursor, eint);

    // ---- weight/bias precompute ----
    wprep_kernel<<<dim3(9, 8), 256, 0, stream>>>(Wrel, Wfc, gma, rvar, Whi, Wlo);
    bias_prep_kernel<<<3, 128, 0, stream>>>(brel, Wfc, bfc, gma, bta, rmean, rvar, bvec);

    // ---- layers (fully fused) ----
    const int GB = (N_NODES + 127) / 128;   // 782
    fused_layer_kernel<<<GB, 512, 0, stream>>>(
        x, rowptr, eint, nd_, Whi, Wlo, h0, bvec, 1);
    fused_layer_kernel<<<GB, 512, 0, stream>>>(
        h0, rowptr, eint, nd_, Whi + (size_t)3 * D * D, Wlo + (size_t)3 * D * D,
        h1, bvec + D, 1);
    fused_layer_kernel<<<GB, 512, 0, stream>>>(
        h1, rowptr, eint, nd_, Whi + (size_t)6 * D * D, Wlo + (size_t)6 * D * D,
        out, bvec + 2 * D, 0);
}